// Round 6
// baseline (402.217 us; speedup 1.0000x reference)
//
#include <hip/hip_runtime.h>
#include <math.h>

#define BB 2
#define NND 10000
#define FF 99
#define NN (BB*NND)
#define MP 20096          /* 157*128 padded rows */
#define EE 160000
#define E2 (BB*EE)
#define DD 128
#define HSTR 256          /* packed h|agg stride */
#define FSTR 192          /* padded feature stride */
#define NLAYERS 4
#define NEMB 64
#define FIN (FF+NEMB)     /* 163 */
#define DFF 512
#define GHD 64
#define RSTART 17
#define RDIM 82
#define SCALE 0.08838834764831845f

typedef __attribute__((ext_vector_type(8))) short bf16x8;
typedef __attribute__((ext_vector_type(4))) float f32x4;
typedef __attribute__((ext_vector_type(4))) unsigned int u32x4;

__device__ __forceinline__ float gelu_f(float v) {
  return 0.5f * v * (1.0f + erff(v * 0.7071067811865475f));
}
__device__ __forceinline__ unsigned short f2b(float f) {
  union { float f; unsigned u; } x; x.f = f;
  unsigned r = x.u + 0x7FFF + ((x.u >> 16) & 1);
  return (unsigned short)(r >> 16);
}
__device__ __forceinline__ float b2f(unsigned short u) {
  union { unsigned u; float f; } x; x.u = ((unsigned)u) << 16;
  return x.f;
}

// async 16B global->LDS (DMA; LDS dest wave-uniform base + lane*16B)
__device__ __forceinline__ void gload_lds16(const unsigned short* g, unsigned short* l) {
  __builtin_amdgcn_global_load_lds(
      (const __attribute__((address_space(1))) unsigned int*)g,
      (__attribute__((address_space(3))) unsigned int*)l, 16, 0, 0);
}

// Stage ROWS x 64 bf16 tile, XOR-swizzled (chunk c of row r lands at slot c^(r&7)),
// via linear LDS dest + inverse-swizzled global source (both-sides rule).
template<int ROWS, int LD>
__device__ __forceinline__ void stage_tile(const unsigned short* __restrict__ G0,
                                           unsigned short* S, int w, int l) {
  constexpr int PER_WAVE = ROWS / 32;
  #pragma unroll
  for (int p = 0; p < PER_WAVE; ++p) {
    int idx = (w * PER_WAVE + p) * 64 + l;      // 16B-chunk linear index
    int row = idx >> 3;
    int c = (idx & 7) ^ (row & 7);              // inverse swizzle on source
    gload_lds16(G0 + (size_t)row * LD + c * 8,
                S + (size_t)(w * PER_WAVE + p) * 512);
  }
}

// ---------------- mega pack: weight converts + featb + zeroing + gate MLP ----------------
#define OQKVW 0
#define OSOW  (OQKVW + NLAYERS*384*DD)
#define OF1   (OSOW  + NLAYERS*DD*256)
#define OF2   (OF1   + NLAYERS*DFF*DD)
#define OWF   (OF2   + NLAYERS*DD*DFF)
#define OQB   (OWF   + DD*FSTR)
#define OSB   (OQB   + NLAYERS*384)
#define OFEAT (OSB   + NLAYERS*DD)
#define ODEG  (OFEAT + (size_t)MP*FSTR)
#define OPAD  (ODEG  + NN)
#define OTOT  (OPAD  + (size_t)(MP-NN)*HSTR)

__global__ void mega_pack(const float* __restrict__ qw, const float* __restrict__ kw,
                          const float* __restrict__ vw, const float* __restrict__ sw,
                          const float* __restrict__ ow, const float* __restrict__ qb,
                          const float* __restrict__ kb, const float* __restrict__ vb,
                          const float* __restrict__ sb, const float* __restrict__ ob,
                          const float* __restrict__ f1w, const float* __restrict__ f2w,
                          const float* __restrict__ W_in,
                          const float* __restrict__ x, const float* __restrict__ emb,
                          const float* __restrict__ g1w, const float* __restrict__ g1b,
                          const float* __restrict__ g2w, const float* __restrict__ g2b,
                          unsigned short* __restrict__ wqkvb, unsigned short* __restrict__ wsow,
                          unsigned short* __restrict__ f1wb, unsigned short* __restrict__ f2wb,
                          unsigned short* __restrict__ wfeat, float* __restrict__ qkvbias,
                          float* __restrict__ sobias, unsigned short* __restrict__ featb,
                          int* __restrict__ deg, unsigned short* __restrict__ hpkpad,
                          float* __restrict__ gamma, float* __restrict__ beta) {
  if (blockIdx.x == gridDim.x - 1) {
    // --- gate MLP block ---
    __shared__ float rain[BB][RDIM];
    __shared__ float act[BB][GHD];
    int t = threadIdx.x;
    for (int idx = t; idx < BB * RDIM; idx += 256) {
      int b = idx / RDIM, j = idx % RDIM;
      rain[b][j] = x[(size_t)b * NND * FF + RSTART + j];
    }
    __syncthreads();
    if (t < BB * GHD) {
      int b = t / GHD, gh = t % GHD;
      float a = g1b[gh];
      for (int j = 0; j < RDIM; ++j) a += rain[b][j] * g1w[gh * RDIM + j];
      act[b][gh] = gelu_f(a);
    }
    __syncthreads();
    for (int idx = t; idx < BB * 2 * DD; idx += 256) {
      int b = idx / (2 * DD), o = idx % (2 * DD);
      float p = g2b[o];
      for (int j = 0; j < GHD; ++j) p += act[b][j] * g2w[o * GHD + j];
      float tv = tanhf(p) * 0.5f;
      if (o < DD) gamma[b * DD + o] = tv;
      else        beta[b * DD + (o - DD)] = tv;
    }
    return;
  }
  size_t i = (size_t)blockIdx.x * 256 + threadIdx.x;
  if (i >= OTOT) return;
  if (i < OSOW) {                     // fused qkv weights
    int kk = i & 127;
    int n = (i >> 7) % 384;
    int lyr = (int)((i >> 7) / 384);
    const float* src = (n < 128) ? qw : (n < 256) ? kw : vw;
    wqkvb[i] = f2b(src[((size_t)lyr * DD + (n & 127)) * DD + kk]);
  } else if (i < OF1) {               // [sw|ow] packed, K=256
    size_t j = i - OSOW;
    int kk = j & 255;
    int n = (j >> 8) & 127;
    int lyr = (int)(j >> 15);
    const float* src = (kk < 128) ? sw : ow;
    wsow[j] = f2b(src[((size_t)lyr * DD + n) * DD + (kk & 127)]);
  } else if (i < OF2) {
    size_t j = i - OF1;
    f1wb[j] = f2b(f1w[j]);
  } else if (i < OWF) {
    size_t j = i - OF2;
    f2wb[j] = f2b(f2w[j]);
  } else if (i < OQB) {               // W_in zero-padded to FSTR
    int j = (int)(i - OWF);
    int kk = j % FSTR, n = j / FSTR;
    wfeat[j] = f2b(kk < FIN ? W_in[n * FIN + kk] : 0.f);
  } else if (i < OSB) {               // qkv bias
    int j = (int)(i - OQB);
    int n = j % 384;
    int lyr = j / 384;
    const float* src = (n < 128) ? qb : (n < 256) ? kb : vb;
    qkvbias[j] = src[lyr * DD + (n & 127)];
  } else if (i < OFEAT) {             // sb+ob
    int j = (int)(i - OSB);
    sobias[j] = sb[j] + ob[j];
  } else if (i < ODEG) {              // featb [MP][192] = [x|emb|0]
    size_t j = i - OFEAT;
    int col = (int)(j % FSTR);
    int node = (int)(j / FSTR);
    float v = 0.f;
    if (node < NN) {
      if (col < FF) v = x[(size_t)node * FF + col];
      else if (col < FIN) v = emb[(size_t)(node % NND) * NEMB + (col - FF)];
    }
    featb[j] = f2b(v);
  } else if (i < OPAD) {              // deg = 0
    deg[(int)(i - ODEG)] = 0;
  } else {                            // hpk pad rows = 0
    hpkpad[i - OPAD] = 0;
  }
}

// ---------------- bf16 MFMA GEMM, 4 waves (2x2), counted-vmcnt pipelined ----------------
// EPI: 0 = bf16 store to Cb (ldc); 2 = relu+resid+LN; 3 = resid+LN; 4 = FiLM
//      5 = split store: col<128 -> Cb (Q, ld 128); col>=128 -> hpk (K|V, ld 256)
//      6 = resid + LN(gs,gb) + final LN(hs2,hb2) + head matmul -> outp (no h/hpk write)
// T4 K-loop: dbuf LDS, raw barriers, vmcnt(N) never 0 mid-loop.
template<int KDIM, int LDA, int LDW, int BM, int BN, int ACT, int EPI>
__global__ __launch_bounds__(256) void mfma_gemm(
    const unsigned short* __restrict__ A, const unsigned short* __restrict__ W,
    const float* __restrict__ bias, unsigned short* __restrict__ Cb, int ldc,
    float* __restrict__ h, unsigned short* __restrict__ hpk,
    const float* __restrict__ gs, const float* __restrict__ gb,
    const float* __restrict__ hs2, const float* __restrict__ hb2,
    const float* __restrict__ hw, const float* __restrict__ hbias,
    float* __restrict__ outp) {
  constexpr int NT = KDIM / 64;
  constexpr int VMC = BM / 32 + BN / 32;   // loads in flight per wave per stage
  __shared__ __align__(16) unsigned short As[2][BM * 64];
  __shared__ __align__(16) unsigned short Ws[2][BN * 64];
  const int tid = threadIdx.x;
  const int w = tid >> 6, l = tid & 63;
  const long mb = (long)blockIdx.x * BM;
  const int nb = blockIdx.y * BN;
  const int wr = (w >> 1) * (BM / 2), wc = (w & 1) * (BN / 2);
  constexpr int MI = BM / 32;
  constexpr int NI = BN / 32;
  f32x4 acc[MI][NI];
  #pragma unroll
  for (int mi = 0; mi < MI; ++mi)
    #pragma unroll
    for (int ni = 0; ni < NI; ++ni) acc[mi][ni] = (f32x4){0.f, 0.f, 0.f, 0.f};

  auto mfma_step = [&](const unsigned short* Ab, const unsigned short* Wb) {
    #pragma unroll
    for (int ks = 0; ks < 2; ++ks) {
      bf16x8 af[MI], bfr[NI];
      #pragma unroll
      for (int mi = 0; mi < MI; ++mi) {
        int ar = wr + mi * 16 + (l & 15);
        int ac = (ks * 4 + (l >> 4)) ^ (ar & 7);
        af[mi] = *(const bf16x8*)&Ab[ar * 64 + ac * 8];
      }
      #pragma unroll
      for (int ni = 0; ni < NI; ++ni) {
        int br = wc + ni * 16 + (l & 15);
        int bc = (ks * 4 + (l >> 4)) ^ (br & 7);
        bfr[ni] = *(const bf16x8*)&Wb[br * 64 + bc * 8];
      }
      #pragma unroll
      for (int mi = 0; mi < MI; ++mi)
        #pragma unroll
        for (int ni = 0; ni < NI; ++ni)
          acc[mi][ni] = __builtin_amdgcn_mfma_f32_16x16x32_bf16(af[mi], bfr[ni], acc[mi][ni], 0, 0, 0);
    }
  };

  // T4: counted vmcnt, loads in flight across raw barriers; never drain to 0 mid-loop.
  stage_tile<BM, LDA>(A + mb * LDA, As[0], w, l);
  stage_tile<BN, LDW>(W + (size_t)nb * LDW, Ws[0], w, l);

  // residual prefetch (EPI 2/3/6): independent of K-loop; hides epilogue load latency.
  float resid[MI][4][NI];
  if constexpr (EPI == 2 || EPI == 3 || EPI == 6) {
    #pragma unroll
    for (int mi = 0; mi < MI; ++mi)
      #pragma unroll
      for (int j = 0; j < 4; ++j)
        #pragma unroll
        for (int ni = 0; ni < NI; ++ni)
          resid[mi][j][ni] =
              h[(mb + wr + mi * 16 + (l >> 4) * 4 + j) * DD + wc + ni * 16 + (l & 15)];
  }

  #pragma unroll
  for (int t = 0; t < NT; ++t) {
    if (t + 1 < NT) {   // issue next tile's loads before computing this one
      stage_tile<BM, LDA>(A + mb * LDA + (t + 1) * 64, As[(t + 1) & 1], w, l);
      stage_tile<BN, LDW>(W + (size_t)nb * LDW + (t + 1) * 64, Ws[(t + 1) & 1], w, l);
      if constexpr (VMC == 5)      asm volatile("s_waitcnt vmcnt(5)" ::: "memory");
      else if constexpr (VMC == 6) asm volatile("s_waitcnt vmcnt(6)" ::: "memory");
      else                         asm volatile("s_waitcnt vmcnt(0)" ::: "memory");
    } else {
      asm volatile("s_waitcnt vmcnt(0)" ::: "memory");
    }
    __builtin_amdgcn_s_barrier();
    __builtin_amdgcn_sched_barrier(0);   // rule 18: block ds_read hoist above barrier
    mfma_step(As[t & 1], Ws[t & 1]);
    __builtin_amdgcn_s_barrier();        // all waves done reading buf before overwrite
  }

  if constexpr (EPI == 0) {
    // frag row=(l>>4)*4+j, col=l&15 (verified r4/r5)
    #pragma unroll
    for (int ni = 0; ni < NI; ++ni) {
      int col = nb + wc + ni * 16 + (l & 15);
      float bi = bias[col];
      #pragma unroll
      for (int mi = 0; mi < MI; ++mi)
        #pragma unroll
        for (int j = 0; j < 4; ++j) {
          long row = mb + wr + mi * 16 + (l >> 4) * 4 + j;
          float vv = acc[mi][ni][j] + bi;
          if (ACT == 1) vv = gelu_f(vv);
          Cb[row * (long)ldc + col] = f2b(vv);
        }
    }
  } else if constexpr (EPI == 5) {
    // split store: Q (cols 0..127) -> Cb stride 128; K|V (cols 128..383) -> hpk stride 256
    #pragma unroll
    for (int ni = 0; ni < NI; ++ni) {
      int col = nb + wc + ni * 16 + (l & 15);
      float bi = bias[col];
      #pragma unroll
      for (int mi = 0; mi < MI; ++mi)
        #pragma unroll
        for (int j = 0; j < 4; ++j) {
          long row = mb + wr + mi * 16 + (l >> 4) * 4 + j;
          float vv = acc[mi][ni][j] + bi;
          if (col < 128) Cb[row * 128 + col] = f2b(vv);
          else           hpk[row * 256 + (col - 128)] = f2b(vv);
        }
    }
  } else if constexpr (EPI == 4) {
    // FiLM: h = (acc+bias)*(1+gamma[b]) + beta[b]
    #pragma unroll
    for (int ni = 0; ni < NI; ++ni) {
      int col = wc + ni * 16 + (l & 15);
      float bi = bias[col];
      float g0 = gs[col], g1 = gs[DD + col];
      float be0 = gb[col], be1 = gb[DD + col];
      #pragma unroll
      for (int mi = 0; mi < MI; ++mi)
        #pragma unroll
        for (int j = 0; j < 4; ++j) {
          long row = mb + wr + mi * 16 + (l >> 4) * 4 + j;
          int b = (row >= NND) ? 1 : 0;
          float v = acc[mi][ni][j] + bi;
          float r = v * (1.0f + (b ? g1 : g0)) + (b ? be1 : be0);
          h[row * DD + col] = r;
          hpk[row * HSTR + col] = f2b(r);
        }
    }
  } else if constexpr (EPI == 2 || EPI == 3) {
    // fused residual (+relu for EPI2) + LayerNorm epilogue; BN==128, nb==0
    __shared__ float ps[2][BM], psq[2][BM];
    float bi[NI];
    #pragma unroll
    for (int ni = 0; ni < NI; ++ni) bi[ni] = bias[wc + ni * 16 + (l & 15)];
    #pragma unroll
    for (int mi = 0; mi < MI; ++mi) {
      #pragma unroll
      for (int j = 0; j < 4; ++j) {
        int r = wr + mi * 16 + (l >> 4) * 4 + j;
        float s = 0.f, sq = 0.f;
        #pragma unroll
        for (int ni = 0; ni < NI; ++ni) {
          float v = acc[mi][ni][j] + bi[ni];
          if (EPI == 2) v = fmaxf(v, 0.f);
          v += resid[mi][j][ni];
          acc[mi][ni][j] = v;
          s += v; sq = fmaf(v, v, sq);
        }
        #pragma unroll
        for (int m = 1; m <= 8; m <<= 1) {
          s += __shfl_xor(s, m);
          sq += __shfl_xor(sq, m);
        }
        if ((l & 15) == 0) { ps[w & 1][r] = s; psq[w & 1][r] = sq; }
      }
    }
    __syncthreads();
    float gsv[NI], gbv[NI];
    #pragma unroll
    for (int ni = 0; ni < NI; ++ni) {
      int col = wc + ni * 16 + (l & 15);
      gsv[ni] = gs[col]; gbv[ni] = gb[col];
    }
    #pragma unroll
    for (int mi = 0; mi < MI; ++mi) {
      #pragma unroll
      for (int j = 0; j < 4; ++j) {
        int r = wr + mi * 16 + (l >> 4) * 4 + j;
        float sum = ps[0][r] + ps[1][r];
        float ssq = psq[0][r] + psq[1][r];
        float mean = sum * (1.0f / 128.0f);
        float var = ssq * (1.0f / 128.0f) - mean * mean;
        float rstd = rsqrtf(var + 1e-5f);
        #pragma unroll
        for (int ni = 0; ni < NI; ++ni) {
          int col = wc + ni * 16 + (l & 15);
          float o = (acc[mi][ni][j] - mean) * rstd * gsv[ni] + gbv[ni];
          h[(mb + r) * DD + col] = o;
          hpk[(mb + r) * HSTR + col] = f2b(o);
        }
      }
    }
  } else if constexpr (EPI == 6) {
    // resid + LN(gs,gb) -> h_final; then LN(hs2,hb2) + head matmul -> outp.
    // No h/hpk writes (nothing reads them after the last layer). MI==1, BN==128.
    __shared__ float ps[2][BM], psq[2][BM];
    float bi[NI], gsv[NI], gbv[NI], hsv[NI], hbv[NI], hw0[NI], hw1[NI];
    #pragma unroll
    for (int ni = 0; ni < NI; ++ni) {
      int col = wc + ni * 16 + (l & 15);
      bi[ni] = bias[col]; gsv[ni] = gs[col]; gbv[ni] = gb[col];
      hsv[ni] = hs2[col]; hbv[ni] = hb2[col];
      hw0[ni] = hw[col];  hw1[ni] = hw[DD + col];
    }
    // pass 1: v = acc+bias+resid, stats1
    #pragma unroll
    for (int j = 0; j < 4; ++j) {
      int r = wr + (l >> 4) * 4 + j;
      float s = 0.f, sq = 0.f;
      #pragma unroll
      for (int ni = 0; ni < NI; ++ni) {
        float v = acc[0][ni][j] + bi[ni] + resid[0][j][ni];
        acc[0][ni][j] = v;
        s += v; sq = fmaf(v, v, sq);
      }
      #pragma unroll
      for (int m = 1; m <= 8; m <<= 1) { s += __shfl_xor(s, m); sq += __shfl_xor(sq, m); }
      if ((l & 15) == 0) { ps[w & 1][r] = s; psq[w & 1][r] = sq; }
    }
    __syncthreads();
    // LN1 -> h_final (in regs), accumulate stats2
    float s2v[4], sq2v[4];
    #pragma unroll
    for (int j = 0; j < 4; ++j) {
      int r = wr + (l >> 4) * 4 + j;
      float mean = (ps[0][r] + ps[1][r]) * (1.0f / 128.0f);
      float var = (psq[0][r] + psq[1][r]) * (1.0f / 128.0f) - mean * mean;
      float rstd = rsqrtf(var + 1e-5f);
      float s2 = 0.f, sq2 = 0.f;
      #pragma unroll
      for (int ni = 0; ni < NI; ++ni) {
        float t = (acc[0][ni][j] - mean) * rstd * gsv[ni] + gbv[ni];
        acc[0][ni][j] = t;
        s2 += t; sq2 = fmaf(t, t, sq2);
      }
      s2v[j] = s2; sq2v[j] = sq2;
    }
    __syncthreads();                 // all waves done reading stats1
    #pragma unroll
    for (int j = 0; j < 4; ++j) {
      int r = wr + (l >> 4) * 4 + j;
      float s = s2v[j], sq = sq2v[j];
      #pragma unroll
      for (int m = 1; m <= 8; m <<= 1) { s += __shfl_xor(s, m); sq += __shfl_xor(sq, m); }
      if ((l & 15) == 0) { ps[w & 1][r] = s; psq[w & 1][r] = sq; }
    }
    __syncthreads();
    // LN2 + head partials
    float p0v[4], p1v[4];
    #pragma unroll
    for (int j = 0; j < 4; ++j) {
      int r = wr + (l >> 4) * 4 + j;
      float mean = (ps[0][r] + ps[1][r]) * (1.0f / 128.0f);
      float var = (psq[0][r] + psq[1][r]) * (1.0f / 128.0f) - mean * mean;
      float rstd = rsqrtf(var + 1e-5f);
      float p0 = 0.f, p1 = 0.f;
      #pragma unroll
      for (int ni = 0; ni < NI; ++ni) {
        float ln = (acc[0][ni][j] - mean) * rstd * hsv[ni] + hbv[ni];
        p0 = fmaf(ln, hw0[ni], p0);
        p1 = fmaf(ln, hw1[ni], p1);
      }
      #pragma unroll
      for (int m = 1; m <= 8; m <<= 1) { p0 += __shfl_xor(p0, m); p1 += __shfl_xor(p1, m); }
      p0v[j] = p0; p1v[j] = p1;
    }
    __syncthreads();                 // done reading stats2
    #pragma unroll
    for (int j = 0; j < 4; ++j) {
      int r = wr + (l >> 4) * 4 + j;
      if ((l & 15) == 0) { ps[w & 1][r] = p0v[j]; psq[w & 1][r] = p1v[j]; }
    }
    __syncthreads();
    if ((w & 1) == 0) {
      #pragma unroll
      for (int j = 0; j < 4; ++j) {
        int r = wr + (l >> 4) * 4 + j;
        if ((l & 15) == 0) {
          long row = mb + r;
          if (row < NN) {
            outp[row] = ps[0][r] + ps[1][r] + hbias[0];
            outp[NN + row] = psq[0][r] + psq[1][r] + hbias[1];
          }
        }
      }
    }
  }
}

// ---------------- CSR build ----------------
__global__ void edge_hist_kernel(const int* __restrict__ eidx, int* __restrict__ deg) {
  int e = blockIdx.x * 256 + threadIdx.x;
  if (e >= E2) return;
  int ei = e % EE, b = e / EE;
  atomicAdd(&deg[eidx[EE + ei] + b * NND], 1);
}

__global__ void scan2_kernel(const int* __restrict__ deg, int* __restrict__ indptr,
                             int* __restrict__ cursor) {
  __shared__ int part[1024];
  int t = threadIdx.x;
  const int CH = 20;
  int beg = t * CH, end = beg + CH;
  if (end > NN) end = NN;
  if (beg > NN) beg = NN;
  int s = 0;
  for (int i = beg; i < end; ++i) s += deg[i];
  part[t] = s;
  __syncthreads();
  for (int off = 1; off < 1024; off <<= 1) {
    int add = (t >= off) ? part[t - off] : 0;
    __syncthreads();
    part[t] += add;
    __syncthreads();
  }
  int run = part[t] - s;
  for (int i = beg; i < end; ++i) {
    indptr[i] = run; cursor[i] = run; run += deg[i];
  }
  if (t == 0) indptr[NN] = E2;
}

__global__ void edge_scatter_kernel(const int* __restrict__ eidx, int* __restrict__ cursor,
                                    int* __restrict__ ssrc) {
  int e = blockIdx.x * 256 + threadIdx.x;
  if (e >= E2) return;
  int ei = e % EE, b = e / EE;
  int srcn = eidx[ei] + b * NND;
  int dstn = eidx[EE + ei] + b * NND;
  int pos = atomicAdd(&cursor[dstn], 1);
  ssrc[pos] = srcn;
}

// ---------------- fused flash-style edge attention (8-lane groups, 2-deep prefetch) ----------------
// 1 wave/node; EIGHT 8-lane groups -> 8 edges/wave in flight x 2 slots = 16 outstanding
// edge-gathers per wave (2x the old 16-lane layout). Each lane loads 32B (2x bf16x8).
// Q from R1 (stride 128); K|V gathered from R2 (stride 256; K at 0, V at 128).
// agg -> hpk[:,128:256].
__global__ __launch_bounds__(256) void fused_attn(
    const unsigned short* __restrict__ q1, const unsigned short* __restrict__ kv,
    const int* __restrict__ ssrc, const int* __restrict__ indptr,
    unsigned short* __restrict__ hpk) {
  int w = threadIdx.x >> 6, l = threadIdx.x & 63;
  int blk = blockIdx.x;
  // bijective batch swizzle (grid = 5000 = 625*8): xcd = blk%8; batch = bit2 of xcd
  int b = (blk >> 2) & 1;
  int i4 = (blk >> 3) * 4 + (blk & 3);      // 0..2499 within batch
  int node = b * NND + i4 * 4 + w;
  int g = l >> 3, sub = l & 7;              // 8 groups x 8 lanes
  int beg = indptr[node], end = indptr[node + 1];
  bf16x8 q0 = *(const bf16x8*)(q1 + (size_t)node * 128 + sub * 16);
  bf16x8 q1r = *(const bf16x8*)(q1 + (size_t)node * 128 + sub * 16 + 8);
  const unsigned short* qu0 = (const unsigned short*)&q0;
  const unsigned short* qu1 = (const unsigned short*)&q1r;
  float m = -INFINITY, den = 0.f;
  float agg[16] = {};
  int p = beg + g;
  bf16x8 k0a, k0b, v0a, v0b, k1a, k1b, v1a, v1b;
  if (p < end) {            // preload slot 0 (edge p)
    const unsigned short* base = kv + (size_t)ssrc[p] * 256 + sub * 16;
    k0a = *(const bf16x8*)(base);
    k0b = *(const bf16x8*)(base + 8);
    v0a = *(const bf16x8*)(base + 128);
    v0b = *(const bf16x8*)(base + 136);
  }
  if (p + 8 < end) {        // preload slot 1 (edge p+8)
    const unsigned short* base = kv + (size_t)ssrc[p + 8] * 256 + sub * 16;
    k1a = *(const bf16x8*)(base);
    k1b = *(const bf16x8*)(base + 8);
    v1a = *(const bf16x8*)(base + 128);
    v1b = *(const bf16x8*)(base + 136);
  }

  auto process = [&](bf16x8 ka, bf16x8 kb, bf16x8 va, bf16x8 vb) {
    const unsigned short* kua = (const unsigned short*)&ka;
    const unsigned short* kub = (const unsigned short*)&kb;
    const unsigned short* vua = (const unsigned short*)&va;
    const unsigned short* vub = (const unsigned short*)&vb;
    float s = 0.f;
    #pragma unroll
    for (int j = 0; j < 8; ++j) s = fmaf(b2f(qu0[j]), b2f(kua[j]), s);
    #pragma unroll
    for (int j = 0; j < 8; ++j) s = fmaf(b2f(qu1[j]), b2f(kub[j]), s);
    s += __shfl_xor(s, 1);
    s += __shfl_xor(s, 2);
    s += __shfl_xor(s, 4);
    s *= SCALE;
    if (s > m + 8.f) {          // defer-max (T13): rescale only on large jumps
      float sc = __expf(m - s); // -inf first time -> 0
      den *= sc;
      #pragma unroll
      for (int j = 0; j < 16; ++j) agg[j] *= sc;
      m = s;
    }
    float e = __expf(s - m);    // bounded by e^8
    den += e;
    #pragma unroll
    for (int j = 0; j < 8; ++j) agg[j] = fmaf(e, b2f(vua[j]), agg[j]);
    #pragma unroll
    for (int j = 0; j < 8; ++j) agg[8 + j] = fmaf(e, b2f(vub[j]), agg[8 + j]);
  };

  while (p < end) {
    {   // consume slot 0 (edge p); refill with edge p+16
      bf16x8 ka = k0a, kb = k0b, va = v0a, vb = v0b;
      if (p + 16 < end) {
        const unsigned short* base = kv + (size_t)ssrc[p + 16] * 256 + sub * 16;
        k0a = *(const bf16x8*)(base);
        k0b = *(const bf16x8*)(base + 8);
        v0a = *(const bf16x8*)(base + 128);
        v0b = *(const bf16x8*)(base + 136);
      }
      process(ka, kb, va, vb);
      p += 8;
      if (p >= end) break;
    }
    {   // consume slot 1 (edge p); refill with edge p+16
      bf16x8 ka = k1a, kb = k1b, va = v1a, vb = v1b;
      if (p + 16 < end) {
        const unsigned short* base = kv + (size_t)ssrc[p + 16] * 256 + sub * 16;
        k1a = *(const bf16x8*)(base);
        k1b = *(const bf16x8*)(base + 8);
        v1a = *(const bf16x8*)(base + 128);
        v1b = *(const bf16x8*)(base + 136);
      }
      process(ka, kb, va, vb);
      p += 8;
    }
  }

  if (beg < end) {
    // cross-group merge over the 8 groups (lanes differing in bits 3,4,5)
    float M = m;
    M = fmaxf(M, __shfl_xor(M, 8));
    M = fmaxf(M, __shfl_xor(M, 16));
    M = fmaxf(M, __shfl_xor(M, 32));
    float sc = __expf(m - M);   // empty group: m=-inf -> 0 (M finite since deg>=1)
    den *= sc;
    #pragma unroll
    for (int j = 0; j < 16; ++j) agg[j] *= sc;
    den += __shfl_xor(den, 8);
    den += __shfl_xor(den, 16);
    den += __shfl_xor(den, 32);
    #pragma unroll
    for (int j = 0; j < 16; ++j) {
      agg[j] += __shfl_xor(agg[j], 8);
      agg[j] += __shfl_xor(agg[j], 16);
      agg[j] += __shfl_xor(agg[j], 32);
    }
    float inv = 1.0f / fmaxf(den, 1e-12f);
    #pragma unroll
    for (int j = 0; j < 16; ++j) agg[j] *= inv;
  }
  if (g == 0) {
    unsigned short o[16];
    #pragma unroll
    for (int j = 0; j < 16; ++j) o[j] = f2b(agg[j]);
    unsigned short* dst = hpk + (size_t)node * HSTR + 128 + sub * 16;
    *(u32x4*)(dst) = *(const u32x4*)(o);
    *(u32x4*)(dst + 8) = *(const u32x4*)(o + 8);
  }
}

extern "C" void kernel_launch(void* const* d_in, const int* in_sizes, int n_in,
                              void* d_out, int out_size, void* d_ws, size_t ws_size,
                              hipStream_t stream) {
  const float* x        = (const float*)d_in[0];
  const int*   eidx     = (const int*)d_in[1];
  const float* node_emb = (const float*)d_in[2];
  const float* W_in     = (const float*)d_in[3];
  const float* b_in     = (const float*)d_in[4];
  const float* g1w      = (const float*)d_in[5];
  const float* g1b      = (const float*)d_in[6];
  const float* g2w      = (const float*)d_in[7];
  const float* g2b      = (const float*)d_in[8];
  const float* qw       = (const float*)d_in[9];
  const float* kw       = (const float*)d_in[10];
  const float* vw       = (const float*)d_in[11];
  const float* sw       = (const float*)d_in[12];
  const float* ow       = (const float*)d_in[13];
  const float* qb       = (const float*)d_in[14];
  const float* kb       = (const float*)d_in[15];
  const float* vb       = (const float*)d_in[16];
  const float* sb       = (const float*)d_in[17];
  const float* ob       = (const float*)d_in[18];
  const float* n1s      = (const float*)d_in[19];
  const float* n1b      = (const float*)d_in[20];
  const float* f1w      = (const float*)d_in[21];
  const float* f1b      = (const float*)d_in[22];
  const float* f2w      = (const float*)d_in[23];
  const float* f2b_     = (const float*)d_in[24];
  const float* n2s      = (const float*)d_in[25];
  const float* n2b      = (const float*)d_in[26];
  const float* hs       = (const float*)d_in[27];
  const float* hb       = (const float*)d_in[28];
  const float* head_w   = (const float*)d_in[29];
  const float* head_b   = (const float*)d_in[30];
  float* out = (float*)d_out;

  float* wsf = (float*)d_ws;
  size_t off = 0;
  auto alloc = [&](size_t nelem) {
    float* p = wsf + off;
    off += (nelem + 63) & ~(size_t)63;
    return p;
  };
  float* gamma  = alloc(BB * DD);
  float* beta   = alloc(BB * DD);
  float* h      = alloc((size_t)MP * DD);
  unsigned short* hpk   = (unsigned short*)alloc((size_t)MP * HSTR / 2);  // h | agg, bf16
  unsigned short* R     = (unsigned short*)alloc((size_t)MP * DFF / 2);   // ff1 out (512)
  unsigned short* R1    = (unsigned short*)alloc((size_t)MP * DD / 2);    // Q, stride 128
  unsigned short* R2    = (unsigned short*)alloc((size_t)MP * 256 / 2);   // K|V, stride 256
  unsigned short* featb = (unsigned short*)alloc((size_t)MP * FSTR / 2);
  int* deg    = (int*)alloc(NN);
  int* indptr = (int*)alloc(NN + 1);
  int* cursor = (int*)alloc(NN);
  int* ssrc   = (int*)alloc(E2);
  unsigned short* wqkvb = (unsigned short*)alloc((size_t)NLAYERS * 384 * DD / 2);
  unsigned short* wsow  = (unsigned short*)alloc((size_t)NLAYERS * DD * 256 / 2);
  unsigned short* f1wb  = (unsigned short*)alloc((size_t)NLAYERS * DFF * DD / 2);
  unsigned short* f2wb  = (unsigned short*)alloc((size_t)NLAYERS * DD * DFF / 2);
  unsigned short* wfeat = (unsigned short*)alloc((size_t)DD * FSTR / 2);
  float* qkvbias = alloc((size_t)NLAYERS * 384);
  float* sobias  = alloc((size_t)NLAYERS * DD);

  if (ws_size < off * sizeof(float)) return;  // clean bail

  // all packing / conversion / zeroing + gate MLP in one dispatch (+1 block for gate)
  mega_pack<<<(int)((OTOT + 255) / 256) + 1, 256, 0, stream>>>(
      qw, kw, vw, sw, ow, qb, kb, vb, sb, ob, f1w, f2w, W_in, x, node_emb,
      g1w, g1b, g2w, g2b,
      wqkvb, wsow, f1wb, f2wb, wfeat, qkvbias, sobias, featb,
      deg, hpk + (size_t)NN * HSTR, gamma, beta);

  edge_hist_kernel<<<(E2 + 255) / 256, 256, 0, stream>>>(eidx, deg);
  scan2_kernel<<<1, 1024, 0, stream>>>(deg, indptr, cursor);
  edge_scatter_kernel<<<(E2 + 255) / 256, 256, 0, stream>>>(eidx, cursor, ssrc);

  const int MB32 = MP / 32;    // 628
  const int MB64 = MP / 64;    // 314
  // input projection + FiLM (EPI=4, pipelined, BM=32)
  mfma_gemm<FSTR, FSTR, FSTR, 32, 128, 0, 4><<<dim3(MB32, 1), 256, 0, stream>>>(
      featb, wfeat, b_in, nullptr, 0, h, hpk, gamma, beta,
      nullptr, nullptr, nullptr, nullptr, nullptr);

  for (int i = 0; i < NLAYERS; ++i) {
    // fused q|k|v; Q -> R1 (128), K|V -> R2 (256)  (EPI=5, BM=64, 942 blocks)
    mfma_gemm<128, HSTR, 128, 64, 128, 0, 5><<<dim3(MB64, 3), 256, 0, stream>>>(
        hpk, wqkvb + (size_t)i * 384 * DD, qkvbias + i * 384, R1, 128,
        nullptr, R2, nullptr, nullptr,
        nullptr, nullptr, nullptr, nullptr, nullptr);
    // flash-style edge attention -> hpk[:,128:256]  (TLP-heavy: 5000 blocks)
    fused_attn<<<NN / 4, 256, 0, stream>>>(R1, R2, ssrc, indptr, hpk);
    // fused [h|agg] @ [sw|ow]^T + (sb+ob), relu, +h, LN  (EPI=2, pipelined, BM=32)
    mfma_gemm<256, HSTR, 256, 32, 128, 0, 2><<<dim3(MB32, 1), 256, 0, stream>>>(
        hpk, wsow + (size_t)i * DD * 256, sobias + i * DD, nullptr, 0,
        h, hpk, n1s + i * DD, n1b + i * DD,
        nullptr, nullptr, nullptr, nullptr, nullptr);
    // ff1 = gelu(h @ f1w^T + f1b) -> R [MP][512]  (BM=64, pipelined, 1256 blocks)
    mfma_gemm<128, HSTR, 128, 64, 128, 1, 0><<<dim3(MB64, 4), 256, 0, stream>>>(
        hpk, f1wb + (size_t)i * DFF * DD, f1b + i * DFF, R, 512,
        nullptr, nullptr, nullptr, nullptr,
        nullptr, nullptr, nullptr, nullptr, nullptr);
    // ff2 + resid + LN (layers 0-2) or + final LN + head (layer 3)
    if (i < NLAYERS - 1) {
      mfma_gemm<512, 512, 512, 32, 128, 0, 3><<<dim3(MB32, 1), 256, 0, stream>>>(
          R, f2wb + (size_t)i * DD * DFF, f2b_ + i * DD, nullptr, 0,
          h, hpk, n2s + i * DD, n2b + i * DD,
          nullptr, nullptr, nullptr, nullptr, nullptr);
    } else {
      mfma_gemm<512, 512, 512, 32, 128, 0, 6><<<dim3(MB32, 1), 256, 0, stream>>>(
          R, f2wb + (size_t)i * DD * DFF, f2b_ + i * DD, nullptr, 0,
          h, hpk, n2s + i * DD, n2b + i * DD,
          hs, hb, head_w, head_b, out);
    }
  }
}

// Round 7
// 389.321 us; speedup vs baseline: 1.0331x; 1.0331x over previous
//
#include <hip/hip_runtime.h>
#include <math.h>

#define BB 2
#define NND 10000
#define FF 99
#define NN (BB*NND)
#define MP 20096          /* 157*128 padded rows */
#define EE 160000
#define E2 (BB*EE)
#define DD 128
#define HSTR 256          /* packed h|agg stride */
#define FSTR 192          /* padded feature stride */
#define NLAYERS 4
#define NEMB 64
#define FIN (FF+NEMB)     /* 163 */
#define DFF 512
#define GHD 64
#define RSTART 17
#define RDIM 82
#define SCALE 0.08838834764831845f

typedef __attribute__((ext_vector_type(8))) short bf16x8;
typedef __attribute__((ext_vector_type(4))) float f32x4;
typedef __attribute__((ext_vector_type(4))) unsigned int u32x4;

__device__ __forceinline__ float gelu_f(float v) {
  return 0.5f * v * (1.0f + erff(v * 0.7071067811865475f));
}
__device__ __forceinline__ unsigned short f2b(float f) {
  union { float f; unsigned u; } x; x.f = f;
  unsigned r = x.u + 0x7FFF + ((x.u >> 16) & 1);
  return (unsigned short)(r >> 16);
}
__device__ __forceinline__ float b2f(unsigned short u) {
  union { unsigned u; float f; } x; x.u = ((unsigned)u) << 16;
  return x.f;
}

// async 16B global->LDS (DMA; LDS dest wave-uniform base + lane*16B)
__device__ __forceinline__ void gload_lds16(const unsigned short* g, unsigned short* l) {
  __builtin_amdgcn_global_load_lds(
      (const __attribute__((address_space(1))) unsigned int*)g,
      (__attribute__((address_space(3))) unsigned int*)l, 16, 0, 0);
}

// Stage ROWS x 64 bf16 tile, XOR-swizzled (chunk c of row r lands at slot c^(r&7)),
// via linear LDS dest + inverse-swizzled global source (both-sides rule).
template<int ROWS, int LD>
__device__ __forceinline__ void stage_tile(const unsigned short* __restrict__ G0,
                                           unsigned short* S, int w, int l) {
  constexpr int PER_WAVE = ROWS / 32;
  #pragma unroll
  for (int p = 0; p < PER_WAVE; ++p) {
    int idx = (w * PER_WAVE + p) * 64 + l;      // 16B-chunk linear index
    int row = idx >> 3;
    int c = (idx & 7) ^ (row & 7);              // inverse swizzle on source
    gload_lds16(G0 + (size_t)row * LD + c * 8,
                S + (size_t)(w * PER_WAVE + p) * 512);
  }
}

// ---------------- mega pack: weight converts + featb + zeroing + gate MLP ----------------
#define OQKVW 0
#define OSOW  (OQKVW + NLAYERS*384*DD)
#define OF1   (OSOW  + NLAYERS*DD*256)
#define OF2   (OF1   + NLAYERS*DFF*DD)
#define OWF   (OF2   + NLAYERS*DD*DFF)
#define OQB   (OWF   + DD*FSTR)
#define OSB   (OQB   + NLAYERS*384)
#define OFEAT (OSB   + NLAYERS*DD)
#define ODEG  (OFEAT + (size_t)MP*FSTR)
#define OPAD  (ODEG  + NN)
#define OTOT  (OPAD  + (size_t)(MP-NN)*HSTR)

__global__ void mega_pack(const float* __restrict__ qw, const float* __restrict__ kw,
                          const float* __restrict__ vw, const float* __restrict__ sw,
                          const float* __restrict__ ow, const float* __restrict__ qb,
                          const float* __restrict__ kb, const float* __restrict__ vb,
                          const float* __restrict__ sb, const float* __restrict__ ob,
                          const float* __restrict__ f1w, const float* __restrict__ f2w,
                          const float* __restrict__ W_in,
                          const float* __restrict__ x, const float* __restrict__ emb,
                          const float* __restrict__ g1w, const float* __restrict__ g1b,
                          const float* __restrict__ g2w, const float* __restrict__ g2b,
                          unsigned short* __restrict__ wqkvb, unsigned short* __restrict__ wsow,
                          unsigned short* __restrict__ f1wb, unsigned short* __restrict__ f2wb,
                          unsigned short* __restrict__ wfeat, float* __restrict__ qkvbias,
                          float* __restrict__ sobias, unsigned short* __restrict__ featb,
                          int* __restrict__ deg, unsigned short* __restrict__ hpkpad,
                          float* __restrict__ gamma, float* __restrict__ beta) {
  if (blockIdx.x == gridDim.x - 1) {
    // --- gate MLP block ---
    __shared__ float rain[BB][RDIM];
    __shared__ float act[BB][GHD];
    int t = threadIdx.x;
    for (int idx = t; idx < BB * RDIM; idx += 256) {
      int b = idx / RDIM, j = idx % RDIM;
      rain[b][j] = x[(size_t)b * NND * FF + RSTART + j];
    }
    __syncthreads();
    if (t < BB * GHD) {
      int b = t / GHD, gh = t % GHD;
      float a = g1b[gh];
      for (int j = 0; j < RDIM; ++j) a += rain[b][j] * g1w[gh * RDIM + j];
      act[b][gh] = gelu_f(a);
    }
    __syncthreads();
    for (int idx = t; idx < BB * 2 * DD; idx += 256) {
      int b = idx / (2 * DD), o = idx % (2 * DD);
      float p = g2b[o];
      for (int j = 0; j < GHD; ++j) p += act[b][j] * g2w[o * GHD + j];
      float tv = tanhf(p) * 0.5f;
      if (o < DD) gamma[b * DD + o] = tv;
      else        beta[b * DD + (o - DD)] = tv;
    }
    return;
  }
  size_t i = (size_t)blockIdx.x * 256 + threadIdx.x;
  if (i >= OTOT) return;
  if (i < OSOW) {                     // fused qkv weights
    int kk = i & 127;
    int n = (i >> 7) % 384;
    int lyr = (int)((i >> 7) / 384);
    const float* src = (n < 128) ? qw : (n < 256) ? kw : vw;
    wqkvb[i] = f2b(src[((size_t)lyr * DD + (n & 127)) * DD + kk]);
  } else if (i < OF1) {               // [sw|ow] packed, K=256
    size_t j = i - OSOW;
    int kk = j & 255;
    int n = (j >> 8) & 127;
    int lyr = (int)(j >> 15);
    const float* src = (kk < 128) ? sw : ow;
    wsow[j] = f2b(src[((size_t)lyr * DD + n) * DD + (kk & 127)]);
  } else if (i < OF2) {
    size_t j = i - OF1;
    f1wb[j] = f2b(f1w[j]);
  } else if (i < OWF) {
    size_t j = i - OF2;
    f2wb[j] = f2b(f2w[j]);
  } else if (i < OQB) {               // W_in zero-padded to FSTR
    int j = (int)(i - OWF);
    int kk = j % FSTR, n = j / FSTR;
    wfeat[j] = f2b(kk < FIN ? W_in[n * FIN + kk] : 0.f);
  } else if (i < OSB) {               // qkv bias
    int j = (int)(i - OQB);
    int n = j % 384;
    int lyr = j / 384;
    const float* src = (n < 128) ? qb : (n < 256) ? kb : vb;
    qkvbias[j] = src[lyr * DD + (n & 127)];
  } else if (i < OFEAT) {             // sb+ob
    int j = (int)(i - OSB);
    sobias[j] = sb[j] + ob[j];
  } else if (i < ODEG) {              // featb [MP][192] = [x|emb|0]
    size_t j = i - OFEAT;
    int col = (int)(j % FSTR);
    int node = (int)(j / FSTR);
    float v = 0.f;
    if (node < NN) {
      if (col < FF) v = x[(size_t)node * FF + col];
      else if (col < FIN) v = emb[(size_t)(node % NND) * NEMB + (col - FF)];
    }
    featb[j] = f2b(v);
  } else if (i < OPAD) {              // deg = 0
    deg[(int)(i - ODEG)] = 0;
  } else {                            // hpk pad rows = 0
    hpkpad[i - OPAD] = 0;
  }
}

// ---------------- bf16 MFMA GEMM, 4 waves (2x2), counted-vmcnt pipelined ----------------
// EPI: 0 = bf16 store to Cb (ldc); 2 = relu+resid+LN; 3 = resid+LN; 4 = FiLM
//      5 = split store: col<128 -> Cb (Q, ld 128); col>=128 -> hpk (K|V, ld 256)
//      6 = resid + LN(gs,gb) + final LN(hs2,hb2) + head matmul -> outp (no h/hpk write)
// T4 K-loop: dbuf LDS, raw barriers, vmcnt(N) never 0 mid-loop.
template<int KDIM, int LDA, int LDW, int BM, int BN, int ACT, int EPI>
__global__ __launch_bounds__(256) void mfma_gemm(
    const unsigned short* __restrict__ A, const unsigned short* __restrict__ W,
    const float* __restrict__ bias, unsigned short* __restrict__ Cb, int ldc,
    float* __restrict__ h, unsigned short* __restrict__ hpk,
    const float* __restrict__ gs, const float* __restrict__ gb,
    const float* __restrict__ hs2, const float* __restrict__ hb2,
    const float* __restrict__ hw, const float* __restrict__ hbias,
    float* __restrict__ outp) {
  constexpr int NT = KDIM / 64;
  constexpr int VMC = BM / 32 + BN / 32;   // loads in flight per wave per stage
  __shared__ __align__(16) unsigned short As[2][BM * 64];
  __shared__ __align__(16) unsigned short Ws[2][BN * 64];
  const int tid = threadIdx.x;
  const int w = tid >> 6, l = tid & 63;
  const long mb = (long)blockIdx.x * BM;
  const int nb = blockIdx.y * BN;
  const int wr = (w >> 1) * (BM / 2), wc = (w & 1) * (BN / 2);
  constexpr int MI = BM / 32;
  constexpr int NI = BN / 32;
  f32x4 acc[MI][NI];
  #pragma unroll
  for (int mi = 0; mi < MI; ++mi)
    #pragma unroll
    for (int ni = 0; ni < NI; ++ni) acc[mi][ni] = (f32x4){0.f, 0.f, 0.f, 0.f};

  auto mfma_step = [&](const unsigned short* Ab, const unsigned short* Wb) {
    #pragma unroll
    for (int ks = 0; ks < 2; ++ks) {
      bf16x8 af[MI], bfr[NI];
      #pragma unroll
      for (int mi = 0; mi < MI; ++mi) {
        int ar = wr + mi * 16 + (l & 15);
        int ac = (ks * 4 + (l >> 4)) ^ (ar & 7);
        af[mi] = *(const bf16x8*)&Ab[ar * 64 + ac * 8];
      }
      #pragma unroll
      for (int ni = 0; ni < NI; ++ni) {
        int br = wc + ni * 16 + (l & 15);
        int bc = (ks * 4 + (l >> 4)) ^ (br & 7);
        bfr[ni] = *(const bf16x8*)&Wb[br * 64 + bc * 8];
      }
      #pragma unroll
      for (int mi = 0; mi < MI; ++mi)
        #pragma unroll
        for (int ni = 0; ni < NI; ++ni)
          acc[mi][ni] = __builtin_amdgcn_mfma_f32_16x16x32_bf16(af[mi], bfr[ni], acc[mi][ni], 0, 0, 0);
    }
  };

  // T4: counted vmcnt, loads in flight across raw barriers; never drain to 0 mid-loop.
  stage_tile<BM, LDA>(A + mb * LDA, As[0], w, l);
  stage_tile<BN, LDW>(W + (size_t)nb * LDW, Ws[0], w, l);

  // residual prefetch (EPI 2/3/6): independent of K-loop; hides epilogue load latency.
  float resid[MI][4][NI];
  if constexpr (EPI == 2 || EPI == 3 || EPI == 6) {
    #pragma unroll
    for (int mi = 0; mi < MI; ++mi)
      #pragma unroll
      for (int j = 0; j < 4; ++j)
        #pragma unroll
        for (int ni = 0; ni < NI; ++ni)
          resid[mi][j][ni] =
              h[(mb + wr + mi * 16 + (l >> 4) * 4 + j) * DD + wc + ni * 16 + (l & 15)];
  }

  #pragma unroll
  for (int t = 0; t < NT; ++t) {
    if (t + 1 < NT) {   // issue next tile's loads before computing this one
      stage_tile<BM, LDA>(A + mb * LDA + (t + 1) * 64, As[(t + 1) & 1], w, l);
      stage_tile<BN, LDW>(W + (size_t)nb * LDW + (t + 1) * 64, Ws[(t + 1) & 1], w, l);
      if constexpr (VMC == 5)      asm volatile("s_waitcnt vmcnt(5)" ::: "memory");
      else if constexpr (VMC == 6) asm volatile("s_waitcnt vmcnt(6)" ::: "memory");
      else                         asm volatile("s_waitcnt vmcnt(0)" ::: "memory");
    } else {
      asm volatile("s_waitcnt vmcnt(0)" ::: "memory");
    }
    __builtin_amdgcn_s_barrier();
    __builtin_amdgcn_sched_barrier(0);   // rule 18: block ds_read hoist above barrier
    mfma_step(As[t & 1], Ws[t & 1]);
    __builtin_amdgcn_s_barrier();        // all waves done reading buf before overwrite
  }

  if constexpr (EPI == 0) {
    // frag row=(l>>4)*4+j, col=l&15 (verified r4/r5)
    #pragma unroll
    for (int ni = 0; ni < NI; ++ni) {
      int col = nb + wc + ni * 16 + (l & 15);
      float bi = bias[col];
      #pragma unroll
      for (int mi = 0; mi < MI; ++mi)
        #pragma unroll
        for (int j = 0; j < 4; ++j) {
          long row = mb + wr + mi * 16 + (l >> 4) * 4 + j;
          float vv = acc[mi][ni][j] + bi;
          if (ACT == 1) vv = gelu_f(vv);
          Cb[row * (long)ldc + col] = f2b(vv);
        }
    }
  } else if constexpr (EPI == 5) {
    // split store: Q (cols 0..127) -> Cb stride 128; K|V (cols 128..383) -> hpk stride 256
    #pragma unroll
    for (int ni = 0; ni < NI; ++ni) {
      int col = nb + wc + ni * 16 + (l & 15);
      float bi = bias[col];
      #pragma unroll
      for (int mi = 0; mi < MI; ++mi)
        #pragma unroll
        for (int j = 0; j < 4; ++j) {
          long row = mb + wr + mi * 16 + (l >> 4) * 4 + j;
          float vv = acc[mi][ni][j] + bi;
          if (col < 128) Cb[row * 128 + col] = f2b(vv);
          else           hpk[row * 256 + (col - 128)] = f2b(vv);
        }
    }
  } else if constexpr (EPI == 4) {
    // FiLM: h = (acc+bias)*(1+gamma[b]) + beta[b]
    #pragma unroll
    for (int ni = 0; ni < NI; ++ni) {
      int col = wc + ni * 16 + (l & 15);
      float bi = bias[col];
      float g0 = gs[col], g1 = gs[DD + col];
      float be0 = gb[col], be1 = gb[DD + col];
      #pragma unroll
      for (int mi = 0; mi < MI; ++mi)
        #pragma unroll
        for (int j = 0; j < 4; ++j) {
          long row = mb + wr + mi * 16 + (l >> 4) * 4 + j;
          int b = (row >= NND) ? 1 : 0;
          float v = acc[mi][ni][j] + bi;
          float r = v * (1.0f + (b ? g1 : g0)) + (b ? be1 : be0);
          h[row * DD + col] = r;
          hpk[row * HSTR + col] = f2b(r);
        }
    }
  } else if constexpr (EPI == 2 || EPI == 3) {
    // fused residual (+relu for EPI2) + LayerNorm epilogue; BN==128, nb==0
    __shared__ float ps[2][BM], psq[2][BM];
    float bi[NI];
    #pragma unroll
    for (int ni = 0; ni < NI; ++ni) bi[ni] = bias[wc + ni * 16 + (l & 15)];
    #pragma unroll
    for (int mi = 0; mi < MI; ++mi) {
      #pragma unroll
      for (int j = 0; j < 4; ++j) {
        int r = wr + mi * 16 + (l >> 4) * 4 + j;
        float s = 0.f, sq = 0.f;
        #pragma unroll
        for (int ni = 0; ni < NI; ++ni) {
          float v = acc[mi][ni][j] + bi[ni];
          if (EPI == 2) v = fmaxf(v, 0.f);
          v += resid[mi][j][ni];
          acc[mi][ni][j] = v;
          s += v; sq = fmaf(v, v, sq);
        }
        #pragma unroll
        for (int m = 1; m <= 8; m <<= 1) {
          s += __shfl_xor(s, m);
          sq += __shfl_xor(sq, m);
        }
        if ((l & 15) == 0) { ps[w & 1][r] = s; psq[w & 1][r] = sq; }
      }
    }
    __syncthreads();
    float gsv[NI], gbv[NI];
    #pragma unroll
    for (int ni = 0; ni < NI; ++ni) {
      int col = wc + ni * 16 + (l & 15);
      gsv[ni] = gs[col]; gbv[ni] = gb[col];
    }
    #pragma unroll
    for (int mi = 0; mi < MI; ++mi) {
      #pragma unroll
      for (int j = 0; j < 4; ++j) {
        int r = wr + mi * 16 + (l >> 4) * 4 + j;
        float sum = ps[0][r] + ps[1][r];
        float ssq = psq[0][r] + psq[1][r];
        float mean = sum * (1.0f / 128.0f);
        float var = ssq * (1.0f / 128.0f) - mean * mean;
        float rstd = rsqrtf(var + 1e-5f);
        #pragma unroll
        for (int ni = 0; ni < NI; ++ni) {
          int col = wc + ni * 16 + (l & 15);
          float o = (acc[mi][ni][j] - mean) * rstd * gsv[ni] + gbv[ni];
          h[(mb + r) * DD + col] = o;
          hpk[(mb + r) * HSTR + col] = f2b(o);
        }
      }
    }
  } else if constexpr (EPI == 6) {
    // resid + LN(gs,gb) -> h_final; then LN(hs2,hb2) + head matmul -> outp.
    // No h/hpk writes (nothing reads them after the last layer). MI==1, BN==128.
    __shared__ float ps[2][BM], psq[2][BM];
    float bi[NI], gsv[NI], gbv[NI], hsv[NI], hbv[NI], hw0[NI], hw1[NI];
    #pragma unroll
    for (int ni = 0; ni < NI; ++ni) {
      int col = wc + ni * 16 + (l & 15);
      bi[ni] = bias[col]; gsv[ni] = gs[col]; gbv[ni] = gb[col];
      hsv[ni] = hs2[col]; hbv[ni] = hb2[col];
      hw0[ni] = hw[col];  hw1[ni] = hw[DD + col];
    }
    // pass 1: v = acc+bias+resid, stats1
    #pragma unroll
    for (int j = 0; j < 4; ++j) {
      int r = wr + (l >> 4) * 4 + j;
      float s = 0.f, sq = 0.f;
      #pragma unroll
      for (int ni = 0; ni < NI; ++ni) {
        float v = acc[0][ni][j] + bi[ni] + resid[0][j][ni];
        acc[0][ni][j] = v;
        s += v; sq = fmaf(v, v, sq);
      }
      #pragma unroll
      for (int m = 1; m <= 8; m <<= 1) { s += __shfl_xor(s, m); sq += __shfl_xor(sq, m); }
      if ((l & 15) == 0) { ps[w & 1][r] = s; psq[w & 1][r] = sq; }
    }
    __syncthreads();
    // LN1 -> h_final (in regs), accumulate stats2
    float s2v[4], sq2v[4];
    #pragma unroll
    for (int j = 0; j < 4; ++j) {
      int r = wr + (l >> 4) * 4 + j;
      float mean = (ps[0][r] + ps[1][r]) * (1.0f / 128.0f);
      float var = (psq[0][r] + psq[1][r]) * (1.0f / 128.0f) - mean * mean;
      float rstd = rsqrtf(var + 1e-5f);
      float s2 = 0.f, sq2 = 0.f;
      #pragma unroll
      for (int ni = 0; ni < NI; ++ni) {
        float t = (acc[0][ni][j] - mean) * rstd * gsv[ni] + gbv[ni];
        acc[0][ni][j] = t;
        s2 += t; sq2 = fmaf(t, t, sq2);
      }
      s2v[j] = s2; sq2v[j] = sq2;
    }
    __syncthreads();                 // all waves done reading stats1
    #pragma unroll
    for (int j = 0; j < 4; ++j) {
      int r = wr + (l >> 4) * 4 + j;
      float s = s2v[j], sq = sq2v[j];
      #pragma unroll
      for (int m = 1; m <= 8; m <<= 1) { s += __shfl_xor(s, m); sq += __shfl_xor(sq, m); }
      if ((l & 15) == 0) { ps[w & 1][r] = s; psq[w & 1][r] = sq; }
    }
    __syncthreads();
    // LN2 + head partials
    float p0v[4], p1v[4];
    #pragma unroll
    for (int j = 0; j < 4; ++j) {
      int r = wr + (l >> 4) * 4 + j;
      float mean = (ps[0][r] + ps[1][r]) * (1.0f / 128.0f);
      float var = (psq[0][r] + psq[1][r]) * (1.0f / 128.0f) - mean * mean;
      float rstd = rsqrtf(var + 1e-5f);
      float p0 = 0.f, p1 = 0.f;
      #pragma unroll
      for (int ni = 0; ni < NI; ++ni) {
        float ln = (acc[0][ni][j] - mean) * rstd * hsv[ni] + hbv[ni];
        p0 = fmaf(ln, hw0[ni], p0);
        p1 = fmaf(ln, hw1[ni], p1);
      }
      #pragma unroll
      for (int m = 1; m <= 8; m <<= 1) { p0 += __shfl_xor(p0, m); p1 += __shfl_xor(p1, m); }
      p0v[j] = p0; p1v[j] = p1;
    }
    __syncthreads();                 // done reading stats2
    #pragma unroll
    for (int j = 0; j < 4; ++j) {
      int r = wr + (l >> 4) * 4 + j;
      if ((l & 15) == 0) { ps[w & 1][r] = p0v[j]; psq[w & 1][r] = p1v[j]; }
    }
    __syncthreads();
    if ((w & 1) == 0) {
      #pragma unroll
      for (int j = 0; j < 4; ++j) {
        int r = wr + (l >> 4) * 4 + j;
        if ((l & 15) == 0) {
          long row = mb + r;
          if (row < NN) {
            outp[row] = ps[0][r] + ps[1][r] + hbias[0];
            outp[NN + row] = psq[0][r] + psq[1][r] + hbias[1];
          }
        }
      }
    }
  }
}

// ---------------- CSR build ----------------
__global__ void edge_hist_kernel(const int* __restrict__ eidx, int* __restrict__ deg) {
  int e = blockIdx.x * 256 + threadIdx.x;
  if (e >= E2) return;
  int ei = e % EE, b = e / EE;
  atomicAdd(&deg[eidx[EE + ei] + b * NND], 1);
}

__global__ void scan2_kernel(const int* __restrict__ deg, int* __restrict__ indptr,
                             int* __restrict__ cursor) {
  __shared__ int part[1024];
  int t = threadIdx.x;
  const int CH = 20;
  int beg = t * CH, end = beg + CH;
  if (end > NN) end = NN;
  if (beg > NN) beg = NN;
  int s = 0;
  for (int i = beg; i < end; ++i) s += deg[i];
  part[t] = s;
  __syncthreads();
  for (int off = 1; off < 1024; off <<= 1) {
    int add = (t >= off) ? part[t - off] : 0;
    __syncthreads();
    part[t] += add;
    __syncthreads();
  }
  int run = part[t] - s;
  for (int i = beg; i < end; ++i) {
    indptr[i] = run; cursor[i] = run; run += deg[i];
  }
  if (t == 0) indptr[NN] = E2;
}

__global__ void edge_scatter_kernel(const int* __restrict__ eidx, int* __restrict__ cursor,
                                    int* __restrict__ ssrc) {
  int e = blockIdx.x * 256 + threadIdx.x;
  if (e >= E2) return;
  int ei = e % EE, b = e / EE;
  int srcn = eidx[ei] + b * NND;
  int dstn = eidx[EE + ei] + b * NND;
  int pos = atomicAdd(&cursor[dstn], 1);
  ssrc[pos] = srcn;
}

// ---------------- fused flash-style edge attention (defer-max + 3-deep prefetch) ----------------
// 1 wave/node; 4 edges in flight per step (16 lanes each), THREE K/V register slots
// (statically indexed, rule #20) -> 12 outstanding edge-gathers per wave.
// Q from R1 (stride 128); K|V gathered from R2 (stride 256; K at 0, V at 128).
// agg -> hpk[:,128:256]. Edge-processing order identical to 1/2-deep -> bit-identical.
__global__ __launch_bounds__(256) void fused_attn(
    const unsigned short* __restrict__ q1, const unsigned short* __restrict__ kv,
    const int* __restrict__ ssrc, const int* __restrict__ indptr,
    unsigned short* __restrict__ hpk) {
  int w = threadIdx.x >> 6, l = threadIdx.x & 63;
  int blk = blockIdx.x;
  // bijective batch swizzle (grid = 5000 = 625*8): xcd = blk%8; batch = bit2 of xcd
  int b = (blk >> 2) & 1;
  int i4 = (blk >> 3) * 4 + (blk & 3);      // 0..2499 within batch
  int node = b * NND + i4 * 4 + w;
  int g = l >> 4, sub = l & 15;
  int beg = indptr[node], end = indptr[node + 1];
  bf16x8 qreg = *(const bf16x8*)(q1 + (size_t)node * 128 + sub * 8);
  const unsigned short* qu = (const unsigned short*)&qreg;
  float m = -INFINITY, den = 0.f;
  float agg[8] = {};
  int p = beg + g;
  bf16x8 kreg0, vreg0, kreg1, vreg1, kreg2, vreg2;
  if (p < end) {            // preload slot 0 (edge p)
    const unsigned short* base = kv + (size_t)ssrc[p] * 256;
    kreg0 = *(const bf16x8*)(base + sub * 8);
    vreg0 = *(const bf16x8*)(base + 128 + sub * 8);
  }
  if (p + 4 < end) {        // preload slot 1 (edge p+4)
    const unsigned short* base = kv + (size_t)ssrc[p + 4] * 256;
    kreg1 = *(const bf16x8*)(base + sub * 8);
    vreg1 = *(const bf16x8*)(base + 128 + sub * 8);
  }
  if (p + 8 < end) {        // preload slot 2 (edge p+8)
    const unsigned short* base = kv + (size_t)ssrc[p + 8] * 256;
    kreg2 = *(const bf16x8*)(base + sub * 8);
    vreg2 = *(const bf16x8*)(base + 128 + sub * 8);
  }

  auto process = [&](bf16x8 kcur, bf16x8 vcur) {
    const unsigned short* ku = (const unsigned short*)&kcur;
    const unsigned short* vu = (const unsigned short*)&vcur;
    float s = 0.f;
    #pragma unroll
    for (int j = 0; j < 8; ++j) s = fmaf(b2f(qu[j]), b2f(ku[j]), s);
    s += __shfl_xor(s, 1);
    s += __shfl_xor(s, 2);
    s += __shfl_xor(s, 4);
    s += __shfl_xor(s, 8);
    s *= SCALE;
    if (s > m + 8.f) {          // defer-max (T13): rescale only on large jumps
      float sc = __expf(m - s); // -inf first time -> 0
      den *= sc;
      #pragma unroll
      for (int j = 0; j < 8; ++j) agg[j] *= sc;
      m = s;
    }
    float e = __expf(s - m);    // bounded by e^8
    den += e;
    #pragma unroll
    for (int j = 0; j < 8; ++j) agg[j] = fmaf(e, b2f(vu[j]), agg[j]);
  };

  while (p < end) {
    {   // consume slot 0 (edge p); refill with edge p+12
      bf16x8 kcur = kreg0, vcur = vreg0;
      if (p + 12 < end) {
        const unsigned short* base = kv + (size_t)ssrc[p + 12] * 256;
        kreg0 = *(const bf16x8*)(base + sub * 8);
        vreg0 = *(const bf16x8*)(base + 128 + sub * 8);
      }
      process(kcur, vcur);
      p += 4;
      if (p >= end) break;
    }
    {   // consume slot 1; refill with edge p+12
      bf16x8 kcur = kreg1, vcur = vreg1;
      if (p + 12 < end) {
        const unsigned short* base = kv + (size_t)ssrc[p + 12] * 256;
        kreg1 = *(const bf16x8*)(base + sub * 8);
        vreg1 = *(const bf16x8*)(base + 128 + sub * 8);
      }
      process(kcur, vcur);
      p += 4;
      if (p >= end) break;
    }
    {   // consume slot 2; refill with edge p+12
      bf16x8 kcur = kreg2, vcur = vreg2;
      if (p + 12 < end) {
        const unsigned short* base = kv + (size_t)ssrc[p + 12] * 256;
        kreg2 = *(const bf16x8*)(base + sub * 8);
        vreg2 = *(const bf16x8*)(base + 128 + sub * 8);
      }
      process(kcur, vcur);
      p += 4;
    }
  }

  if (beg < end) {
    float M = m;
    M = fmaxf(M, __shfl_xor(M, 16));
    M = fmaxf(M, __shfl_xor(M, 32));
    float sc = __expf(m - M);   // empty group: m=-inf -> 0
    den *= sc;
    #pragma unroll
    for (int j = 0; j < 8; ++j) agg[j] *= sc;
    den += __shfl_xor(den, 16);
    den += __shfl_xor(den, 32);
    #pragma unroll
    for (int j = 0; j < 8; ++j) {
      agg[j] += __shfl_xor(agg[j], 16);
      agg[j] += __shfl_xor(agg[j], 32);
    }
    float inv = 1.0f / fmaxf(den, 1e-12f);
    #pragma unroll
    for (int j = 0; j < 8; ++j) agg[j] *= inv;
  }
  if (g == 0) {
    unsigned short o[8];
    #pragma unroll
    for (int j = 0; j < 8; ++j) o[j] = f2b(agg[j]);
    *(u32x4*)(hpk + (size_t)node * HSTR + 128 + sub * 8) = *(const u32x4*)o;
  }
}

extern "C" void kernel_launch(void* const* d_in, const int* in_sizes, int n_in,
                              void* d_out, int out_size, void* d_ws, size_t ws_size,
                              hipStream_t stream) {
  const float* x        = (const float*)d_in[0];
  const int*   eidx     = (const int*)d_in[1];
  const float* node_emb = (const float*)d_in[2];
  const float* W_in     = (const float*)d_in[3];
  const float* b_in     = (const float*)d_in[4];
  const float* g1w      = (const float*)d_in[5];
  const float* g1b      = (const float*)d_in[6];
  const float* g2w      = (const float*)d_in[7];
  const float* g2b      = (const float*)d_in[8];
  const float* qw       = (const float*)d_in[9];
  const float* kw       = (const float*)d_in[10];
  const float* vw       = (const float*)d_in[11];
  const float* sw       = (const float*)d_in[12];
  const float* ow       = (const float*)d_in[13];
  const float* qb       = (const float*)d_in[14];
  const float* kb       = (const float*)d_in[15];
  const float* vb       = (const float*)d_in[16];
  const float* sb       = (const float*)d_in[17];
  const float* ob       = (const float*)d_in[18];
  const float* n1s      = (const float*)d_in[19];
  const float* n1b      = (const float*)d_in[20];
  const float* f1w      = (const float*)d_in[21];
  const float* f1b      = (const float*)d_in[22];
  const float* f2w      = (const float*)d_in[23];
  const float* f2b_     = (const float*)d_in[24];
  const float* n2s      = (const float*)d_in[25];
  const float* n2b      = (const float*)d_in[26];
  const float* hs       = (const float*)d_in[27];
  const float* hb       = (const float*)d_in[28];
  const float* head_w   = (const float*)d_in[29];
  const float* head_b   = (const float*)d_in[30];
  float* out = (float*)d_out;

  float* wsf = (float*)d_ws;
  size_t off = 0;
  auto alloc = [&](size_t nelem) {
    float* p = wsf + off;
    off += (nelem + 63) & ~(size_t)63;
    return p;
  };
  float* gamma  = alloc(BB * DD);
  float* beta   = alloc(BB * DD);
  float* h      = alloc((size_t)MP * DD);
  unsigned short* hpk   = (unsigned short*)alloc((size_t)MP * HSTR / 2);  // h | agg, bf16
  unsigned short* R     = (unsigned short*)alloc((size_t)MP * DFF / 2);   // ff1 out (512)
  unsigned short* R1    = (unsigned short*)alloc((size_t)MP * DD / 2);    // Q, stride 128
  unsigned short* R2    = (unsigned short*)alloc((size_t)MP * 256 / 2);   // K|V, stride 256
  unsigned short* featb = (unsigned short*)alloc((size_t)MP * FSTR / 2);
  int* deg    = (int*)alloc(NN);
  int* indptr = (int*)alloc(NN + 1);
  int* cursor = (int*)alloc(NN);
  int* ssrc   = (int*)alloc(E2);
  unsigned short* wqkvb = (unsigned short*)alloc((size_t)NLAYERS * 384 * DD / 2);
  unsigned short* wsow  = (unsigned short*)alloc((size_t)NLAYERS * DD * 256 / 2);
  unsigned short* f1wb  = (unsigned short*)alloc((size_t)NLAYERS * DFF * DD / 2);
  unsigned short* f2wb  = (unsigned short*)alloc((size_t)NLAYERS * DD * DFF / 2);
  unsigned short* wfeat = (unsigned short*)alloc((size_t)DD * FSTR / 2);
  float* qkvbias = alloc((size_t)NLAYERS * 384);
  float* sobias  = alloc((size_t)NLAYERS * DD);

  if (ws_size < off * sizeof(float)) return;  // clean bail

  // all packing / conversion / zeroing + gate MLP in one dispatch (+1 block for gate)
  mega_pack<<<(int)((OTOT + 255) / 256) + 1, 256, 0, stream>>>(
      qw, kw, vw, sw, ow, qb, kb, vb, sb, ob, f1w, f2w, W_in, x, node_emb,
      g1w, g1b, g2w, g2b,
      wqkvb, wsow, f1wb, f2wb, wfeat, qkvbias, sobias, featb,
      deg, hpk + (size_t)NN * HSTR, gamma, beta);

  edge_hist_kernel<<<(E2 + 255) / 256, 256, 0, stream>>>(eidx, deg);
  scan2_kernel<<<1, 1024, 0, stream>>>(deg, indptr, cursor);
  edge_scatter_kernel<<<(E2 + 255) / 256, 256, 0, stream>>>(eidx, cursor, ssrc);

  const int MB32 = MP / 32;    // 628
  const int MB64 = MP / 64;    // 314
  // input projection + FiLM (EPI=4, pipelined, BM=32)
  mfma_gemm<FSTR, FSTR, FSTR, 32, 128, 0, 4><<<dim3(MB32, 1), 256, 0, stream>>>(
      featb, wfeat, b_in, nullptr, 0, h, hpk, gamma, beta,
      nullptr, nullptr, nullptr, nullptr, nullptr);

  for (int i = 0; i < NLAYERS; ++i) {
    // fused q|k|v; Q -> R1 (128), K|V -> R2 (256)  (EPI=5, BM=64, 942 blocks)
    mfma_gemm<128, HSTR, 128, 64, 128, 0, 5><<<dim3(MB64, 3), 256, 0, stream>>>(
        hpk, wqkvb + (size_t)i * 384 * DD, qkvbias + i * 384, R1, 128,
        nullptr, R2, nullptr, nullptr,
        nullptr, nullptr, nullptr, nullptr, nullptr);
    // flash-style edge attention -> hpk[:,128:256]  (TLP-heavy: 5000 blocks)
    fused_attn<<<NN / 4, 256, 0, stream>>>(R1, R2, ssrc, indptr, hpk);
    // fused [h|agg] @ [sw|ow]^T + (sb+ob), relu, +h, LN  (EPI=2, pipelined, BM=32)
    mfma_gemm<256, HSTR, 256, 32, 128, 0, 2><<<dim3(MB32, 1), 256, 0, stream>>>(
        hpk, wsow + (size_t)i * DD * 256, sobias + i * DD, nullptr, 0,
        h, hpk, n1s + i * DD, n1b + i * DD,
        nullptr, nullptr, nullptr, nullptr, nullptr);
    // ff1 = gelu(h @ f1w^T + f1b) -> R [MP][512]  (BM=64, pipelined, 1256 blocks)
    mfma_gemm<128, HSTR, 128, 64, 128, 1, 0><<<dim3(MB64, 4), 256, 0, stream>>>(
        hpk, f1wb + (size_t)i * DFF * DD, f1b + i * DFF, R, 512,
        nullptr, nullptr, nullptr, nullptr,
        nullptr, nullptr, nullptr, nullptr, nullptr);
    // ff2 + resid + LN (layers 0-2) or + final LN + head (layer 3)
    if (i < NLAYERS - 1) {
      mfma_gemm<512, 512, 512, 32, 128, 0, 3><<<dim3(MB32, 1), 256, 0, stream>>>(
          R, f2wb + (size_t)i * DD * DFF, f2b_ + i * DD, nullptr, 0,
          h, hpk, n2s + i * DD, n2b + i * DD,
          nullptr, nullptr, nullptr, nullptr, nullptr);
    } else {
      mfma_gemm<512, 512, 512, 32, 128, 0, 6><<<dim3(MB32, 1), 256, 0, stream>>>(
          R, f2wb + (size_t)i * DD * DFF, f2b_ + i * DD, nullptr, 0,
          h, hpk, n2s + i * DD, n2b + i * DD,
          hs, hb, head_w, head_b, out);
    }
  }
}

// Round 8
// 381.128 us; speedup vs baseline: 1.0553x; 1.0215x over previous
//
#include <hip/hip_runtime.h>
#include <math.h>

#define BB 2
#define NND 10000
#define FF 99
#define NN (BB*NND)
#define MP 20096          /* 157*128 padded rows */
#define EE 160000
#define E2 (BB*EE)
#define DD 128
#define HSTR 256          /* packed h|agg stride */
#define FSTR 192          /* padded feature stride */
#define NLAYERS 4
#define NEMB 64
#define FIN (FF+NEMB)     /* 163 */
#define DFF 512
#define GHD 64
#define RSTART 17
#define RDIM 82
#define SCALE 0.08838834764831845f

typedef __attribute__((ext_vector_type(8))) short bf16x8;
typedef __attribute__((ext_vector_type(4))) float f32x4;
typedef __attribute__((ext_vector_type(4))) unsigned int u32x4;

__device__ __forceinline__ float gelu_f(float v) {
  return 0.5f * v * (1.0f + erff(v * 0.7071067811865475f));
}
__device__ __forceinline__ unsigned short f2b(float f) {
  union { float f; unsigned u; } x; x.f = f;
  unsigned r = x.u + 0x7FFF + ((x.u >> 16) & 1);
  return (unsigned short)(r >> 16);
}
__device__ __forceinline__ float b2f(unsigned short u) {
  union { unsigned u; float f; } x; x.u = ((unsigned)u) << 16;
  return x.f;
}

// async 16B global->LDS (DMA; LDS dest wave-uniform base + lane*16B)
__device__ __forceinline__ void gload_lds16(const unsigned short* g, unsigned short* l) {
  __builtin_amdgcn_global_load_lds(
      (const __attribute__((address_space(1))) unsigned int*)g,
      (__attribute__((address_space(3))) unsigned int*)l, 16, 0, 0);
}

// Stage ROWS x 64 bf16 tile, XOR-swizzled (chunk c of row r lands at slot c^(r&7)),
// via linear LDS dest + inverse-swizzled global source (both-sides rule).
template<int ROWS, int LD>
__device__ __forceinline__ void stage_tile(const unsigned short* __restrict__ G0,
                                           unsigned short* S, int w, int l) {
  constexpr int PER_WAVE = ROWS / 32;
  #pragma unroll
  for (int p = 0; p < PER_WAVE; ++p) {
    int idx = (w * PER_WAVE + p) * 64 + l;      // 16B-chunk linear index
    int row = idx >> 3;
    int c = (idx & 7) ^ (row & 7);              // inverse swizzle on source
    gload_lds16(G0 + (size_t)row * LD + c * 8,
                S + (size_t)(w * PER_WAVE + p) * 512);
  }
}

// ---------------- mega pack: weight converts + featb + zeroing + gate MLP ----------------
#define OQKVW 0
#define OSOW  (OQKVW + NLAYERS*384*DD)
#define OF1   (OSOW  + NLAYERS*DD*256)
#define OF2   (OF1   + NLAYERS*DFF*DD)
#define OWF   (OF2   + NLAYERS*DD*DFF)
#define OQB   (OWF   + DD*FSTR)
#define OSB   (OQB   + NLAYERS*384)
#define OFEAT (OSB   + NLAYERS*DD)
#define ODEG  (OFEAT + (size_t)MP*FSTR)
#define OPAD  (ODEG  + NN)
#define OTOT  (OPAD  + (size_t)(MP-NN)*HSTR)

__global__ void mega_pack(const float* __restrict__ qw, const float* __restrict__ kw,
                          const float* __restrict__ vw, const float* __restrict__ sw,
                          const float* __restrict__ ow, const float* __restrict__ qb,
                          const float* __restrict__ kb, const float* __restrict__ vb,
                          const float* __restrict__ sb, const float* __restrict__ ob,
                          const float* __restrict__ f1w, const float* __restrict__ f2w,
                          const float* __restrict__ W_in,
                          const float* __restrict__ x, const float* __restrict__ emb,
                          const float* __restrict__ g1w, const float* __restrict__ g1b,
                          const float* __restrict__ g2w, const float* __restrict__ g2b,
                          unsigned short* __restrict__ wqkvb, unsigned short* __restrict__ wsow,
                          unsigned short* __restrict__ f1wb, unsigned short* __restrict__ f2wb,
                          unsigned short* __restrict__ wfeat, float* __restrict__ qkvbias,
                          float* __restrict__ sobias, unsigned short* __restrict__ featb,
                          int* __restrict__ deg, unsigned short* __restrict__ hpkpad,
                          float* __restrict__ gamma, float* __restrict__ beta) {
  if (blockIdx.x == gridDim.x - 1) {
    // --- gate MLP block ---
    __shared__ float rain[BB][RDIM];
    __shared__ float act[BB][GHD];
    int t = threadIdx.x;
    for (int idx = t; idx < BB * RDIM; idx += 256) {
      int b = idx / RDIM, j = idx % RDIM;
      rain[b][j] = x[(size_t)b * NND * FF + RSTART + j];
    }
    __syncthreads();
    if (t < BB * GHD) {
      int b = t / GHD, gh = t % GHD;
      float a = g1b[gh];
      for (int j = 0; j < RDIM; ++j) a += rain[b][j] * g1w[gh * RDIM + j];
      act[b][gh] = gelu_f(a);
    }
    __syncthreads();
    for (int idx = t; idx < BB * 2 * DD; idx += 256) {
      int b = idx / (2 * DD), o = idx % (2 * DD);
      float p = g2b[o];
      for (int j = 0; j < GHD; ++j) p += act[b][j] * g2w[o * GHD + j];
      float tv = tanhf(p) * 0.5f;
      if (o < DD) gamma[b * DD + o] = tv;
      else        beta[b * DD + (o - DD)] = tv;
    }
    return;
  }
  size_t i = (size_t)blockIdx.x * 256 + threadIdx.x;
  if (i >= OTOT) return;
  if (i < OSOW) {                     // fused qkv weights
    int kk = i & 127;
    int n = (i >> 7) % 384;
    int lyr = (int)((i >> 7) / 384);
    const float* src = (n < 128) ? qw : (n < 256) ? kw : vw;
    wqkvb[i] = f2b(src[((size_t)lyr * DD + (n & 127)) * DD + kk]);
  } else if (i < OF1) {               // [sw|ow] packed, K=256
    size_t j = i - OSOW;
    int kk = j & 255;
    int n = (j >> 8) & 127;
    int lyr = (int)(j >> 15);
    const float* src = (kk < 128) ? sw : ow;
    wsow[j] = f2b(src[((size_t)lyr * DD + n) * DD + (kk & 127)]);
  } else if (i < OF2) {
    size_t j = i - OF1;
    f1wb[j] = f2b(f1w[j]);
  } else if (i < OWF) {
    size_t j = i - OF2;
    f2wb[j] = f2b(f2w[j]);
  } else if (i < OQB) {               // W_in zero-padded to FSTR
    int j = (int)(i - OWF);
    int kk = j % FSTR, n = j / FSTR;
    wfeat[j] = f2b(kk < FIN ? W_in[n * FIN + kk] : 0.f);
  } else if (i < OSB) {               // qkv bias
    int j = (int)(i - OQB);
    int n = j % 384;
    int lyr = j / 384;
    const float* src = (n < 128) ? qb : (n < 256) ? kb : vb;
    qkvbias[j] = src[lyr * DD + (n & 127)];
  } else if (i < OFEAT) {             // sb+ob
    int j = (int)(i - OSB);
    sobias[j] = sb[j] + ob[j];
  } else if (i < ODEG) {              // featb [MP][192] = [x|emb|0]
    size_t j = i - OFEAT;
    int col = (int)(j % FSTR);
    int node = (int)(j / FSTR);
    float v = 0.f;
    if (node < NN) {
      if (col < FF) v = x[(size_t)node * FF + col];
      else if (col < FIN) v = emb[(size_t)(node % NND) * NEMB + (col - FF)];
    }
    featb[j] = f2b(v);
  } else if (i < OPAD) {              // deg = 0
    deg[(int)(i - ODEG)] = 0;
  } else {                            // hpk pad rows = 0
    hpkpad[i - OPAD] = 0;
  }
}

// ---------------- bf16 MFMA GEMM, 4 waves (2x2), counted-vmcnt pipelined ----------------
// EPI: 0 = bf16 store to Cb (ldc); 2 = relu+resid+LN; 3 = resid+LN; 4 = FiLM
//      5 = split store: col<128 -> Cb (Q, ld 128); col>=128 -> hpk (K|V, ld 256)
//      6 = resid + LN(gs,gb) + final LN(hs2,hb2) + head matmul -> outp (no h/hpk write)
// T4 K-loop: dbuf LDS, raw barriers, vmcnt(N) never 0 mid-loop.
template<int KDIM, int LDA, int LDW, int BM, int BN, int ACT, int EPI>
__global__ __launch_bounds__(256) void mfma_gemm(
    const unsigned short* __restrict__ A, const unsigned short* __restrict__ W,
    const float* __restrict__ bias, unsigned short* __restrict__ Cb, int ldc,
    float* __restrict__ h, unsigned short* __restrict__ hpk,
    const float* __restrict__ gs, const float* __restrict__ gb,
    const float* __restrict__ hs2, const float* __restrict__ hb2,
    const float* __restrict__ hw, const float* __restrict__ hbias,
    float* __restrict__ outp) {
  constexpr int NT = KDIM / 64;
  constexpr int VMC = BM / 32 + BN / 32;   // loads in flight per wave per stage
  __shared__ __align__(16) unsigned short As[2][BM * 64];
  __shared__ __align__(16) unsigned short Ws[2][BN * 64];
  const int tid = threadIdx.x;
  const int w = tid >> 6, l = tid & 63;
  const long mb = (long)blockIdx.x * BM;
  const int nb = blockIdx.y * BN;
  const int wr = (w >> 1) * (BM / 2), wc = (w & 1) * (BN / 2);
  constexpr int MI = BM / 32;
  constexpr int NI = BN / 32;
  f32x4 acc[MI][NI];
  #pragma unroll
  for (int mi = 0; mi < MI; ++mi)
    #pragma unroll
    for (int ni = 0; ni < NI; ++ni) acc[mi][ni] = (f32x4){0.f, 0.f, 0.f, 0.f};

  auto mfma_step = [&](const unsigned short* Ab, const unsigned short* Wb) {
    #pragma unroll
    for (int ks = 0; ks < 2; ++ks) {
      bf16x8 af[MI], bfr[NI];
      #pragma unroll
      for (int mi = 0; mi < MI; ++mi) {
        int ar = wr + mi * 16 + (l & 15);
        int ac = (ks * 4 + (l >> 4)) ^ (ar & 7);
        af[mi] = *(const bf16x8*)&Ab[ar * 64 + ac * 8];
      }
      #pragma unroll
      for (int ni = 0; ni < NI; ++ni) {
        int br = wc + ni * 16 + (l & 15);
        int bc = (ks * 4 + (l >> 4)) ^ (br & 7);
        bfr[ni] = *(const bf16x8*)&Wb[br * 64 + bc * 8];
      }
      #pragma unroll
      for (int mi = 0; mi < MI; ++mi)
        #pragma unroll
        for (int ni = 0; ni < NI; ++ni)
          acc[mi][ni] = __builtin_amdgcn_mfma_f32_16x16x32_bf16(af[mi], bfr[ni], acc[mi][ni], 0, 0, 0);
    }
  };

  // T4: counted vmcnt, loads in flight across raw barriers; never drain to 0 mid-loop.
  stage_tile<BM, LDA>(A + mb * LDA, As[0], w, l);
  stage_tile<BN, LDW>(W + (size_t)nb * LDW, Ws[0], w, l);

  // residual prefetch (EPI 2/3/6): independent of K-loop; hides epilogue load latency.
  float resid[MI][4][NI];
  if constexpr (EPI == 2 || EPI == 3 || EPI == 6) {
    #pragma unroll
    for (int mi = 0; mi < MI; ++mi)
      #pragma unroll
      for (int j = 0; j < 4; ++j)
        #pragma unroll
        for (int ni = 0; ni < NI; ++ni)
          resid[mi][j][ni] =
              h[(mb + wr + mi * 16 + (l >> 4) * 4 + j) * DD + wc + ni * 16 + (l & 15)];
  }

  #pragma unroll
  for (int t = 0; t < NT; ++t) {
    if (t + 1 < NT) {   // issue next tile's loads before computing this one
      stage_tile<BM, LDA>(A + mb * LDA + (t + 1) * 64, As[(t + 1) & 1], w, l);
      stage_tile<BN, LDW>(W + (size_t)nb * LDW + (t + 1) * 64, Ws[(t + 1) & 1], w, l);
      if constexpr (VMC == 5)      asm volatile("s_waitcnt vmcnt(5)" ::: "memory");
      else if constexpr (VMC == 6) asm volatile("s_waitcnt vmcnt(6)" ::: "memory");
      else                         asm volatile("s_waitcnt vmcnt(0)" ::: "memory");
    } else {
      asm volatile("s_waitcnt vmcnt(0)" ::: "memory");
    }
    __builtin_amdgcn_s_barrier();
    __builtin_amdgcn_sched_barrier(0);   // rule 18: block ds_read hoist above barrier
    mfma_step(As[t & 1], Ws[t & 1]);
    __builtin_amdgcn_s_barrier();        // all waves done reading buf before overwrite
  }

  if constexpr (EPI == 0) {
    // frag row=(l>>4)*4+j, col=l&15 (verified r4/r5)
    #pragma unroll
    for (int ni = 0; ni < NI; ++ni) {
      int col = nb + wc + ni * 16 + (l & 15);
      float bi = bias[col];
      #pragma unroll
      for (int mi = 0; mi < MI; ++mi)
        #pragma unroll
        for (int j = 0; j < 4; ++j) {
          long row = mb + wr + mi * 16 + (l >> 4) * 4 + j;
          float vv = acc[mi][ni][j] + bi;
          if (ACT == 1) vv = gelu_f(vv);
          Cb[row * (long)ldc + col] = f2b(vv);
        }
    }
  } else if constexpr (EPI == 5) {
    // split store: Q (cols 0..127) -> Cb stride 128; K|V (cols 128..383) -> hpk stride 256
    #pragma unroll
    for (int ni = 0; ni < NI; ++ni) {
      int col = nb + wc + ni * 16 + (l & 15);
      float bi = bias[col];
      #pragma unroll
      for (int mi = 0; mi < MI; ++mi)
        #pragma unroll
        for (int j = 0; j < 4; ++j) {
          long row = mb + wr + mi * 16 + (l >> 4) * 4 + j;
          float vv = acc[mi][ni][j] + bi;
          if (col < 128) Cb[row * 128 + col] = f2b(vv);
          else           hpk[row * 256 + (col - 128)] = f2b(vv);
        }
    }
  } else if constexpr (EPI == 4) {
    // FiLM: h = (acc+bias)*(1+gamma[b]) + beta[b]
    #pragma unroll
    for (int ni = 0; ni < NI; ++ni) {
      int col = wc + ni * 16 + (l & 15);
      float bi = bias[col];
      float g0 = gs[col], g1 = gs[DD + col];
      float be0 = gb[col], be1 = gb[DD + col];
      #pragma unroll
      for (int mi = 0; mi < MI; ++mi)
        #pragma unroll
        for (int j = 0; j < 4; ++j) {
          long row = mb + wr + mi * 16 + (l >> 4) * 4 + j;
          int b = (row >= NND) ? 1 : 0;
          float v = acc[mi][ni][j] + bi;
          float r = v * (1.0f + (b ? g1 : g0)) + (b ? be1 : be0);
          h[row * DD + col] = r;
          hpk[row * HSTR + col] = f2b(r);
        }
    }
  } else if constexpr (EPI == 2 || EPI == 3) {
    // fused residual (+relu for EPI2) + LayerNorm epilogue; BN==128, nb==0
    __shared__ float ps[2][BM], psq[2][BM];
    float bi[NI];
    #pragma unroll
    for (int ni = 0; ni < NI; ++ni) bi[ni] = bias[wc + ni * 16 + (l & 15)];
    #pragma unroll
    for (int mi = 0; mi < MI; ++mi) {
      #pragma unroll
      for (int j = 0; j < 4; ++j) {
        int r = wr + mi * 16 + (l >> 4) * 4 + j;
        float s = 0.f, sq = 0.f;
        #pragma unroll
        for (int ni = 0; ni < NI; ++ni) {
          float v = acc[mi][ni][j] + bi[ni];
          if (EPI == 2) v = fmaxf(v, 0.f);
          v += resid[mi][j][ni];
          acc[mi][ni][j] = v;
          s += v; sq = fmaf(v, v, sq);
        }
        #pragma unroll
        for (int m = 1; m <= 8; m <<= 1) {
          s += __shfl_xor(s, m);
          sq += __shfl_xor(sq, m);
        }
        if ((l & 15) == 0) { ps[w & 1][r] = s; psq[w & 1][r] = sq; }
      }
    }
    __syncthreads();
    float gsv[NI], gbv[NI];
    #pragma unroll
    for (int ni = 0; ni < NI; ++ni) {
      int col = wc + ni * 16 + (l & 15);
      gsv[ni] = gs[col]; gbv[ni] = gb[col];
    }
    #pragma unroll
    for (int mi = 0; mi < MI; ++mi) {
      #pragma unroll
      for (int j = 0; j < 4; ++j) {
        int r = wr + mi * 16 + (l >> 4) * 4 + j;
        float sum = ps[0][r] + ps[1][r];
        float ssq = psq[0][r] + psq[1][r];
        float mean = sum * (1.0f / 128.0f);
        float var = ssq * (1.0f / 128.0f) - mean * mean;
        float rstd = rsqrtf(var + 1e-5f);
        #pragma unroll
        for (int ni = 0; ni < NI; ++ni) {
          int col = wc + ni * 16 + (l & 15);
          float o = (acc[mi][ni][j] - mean) * rstd * gsv[ni] + gbv[ni];
          h[(mb + r) * DD + col] = o;
          hpk[(mb + r) * HSTR + col] = f2b(o);
        }
      }
    }
  } else if constexpr (EPI == 6) {
    // resid + LN(gs,gb) -> h_final; then LN(hs2,hb2) + head matmul -> outp.
    // No h/hpk writes (nothing reads them after the last layer). MI==1, BN==128.
    __shared__ float ps[2][BM], psq[2][BM];
    float bi[NI], gsv[NI], gbv[NI], hsv[NI], hbv[NI], hw0[NI], hw1[NI];
    #pragma unroll
    for (int ni = 0; ni < NI; ++ni) {
      int col = wc + ni * 16 + (l & 15);
      bi[ni] = bias[col]; gsv[ni] = gs[col]; gbv[ni] = gb[col];
      hsv[ni] = hs2[col]; hbv[ni] = hb2[col];
      hw0[ni] = hw[col];  hw1[ni] = hw[DD + col];
    }
    // pass 1: v = acc+bias+resid, stats1
    #pragma unroll
    for (int j = 0; j < 4; ++j) {
      int r = wr + (l >> 4) * 4 + j;
      float s = 0.f, sq = 0.f;
      #pragma unroll
      for (int ni = 0; ni < NI; ++ni) {
        float v = acc[0][ni][j] + bi[ni] + resid[0][j][ni];
        acc[0][ni][j] = v;
        s += v; sq = fmaf(v, v, sq);
      }
      #pragma unroll
      for (int m = 1; m <= 8; m <<= 1) { s += __shfl_xor(s, m); sq += __shfl_xor(sq, m); }
      if ((l & 15) == 0) { ps[w & 1][r] = s; psq[w & 1][r] = sq; }
    }
    __syncthreads();
    // LN1 -> h_final (in regs), accumulate stats2
    float s2v[4], sq2v[4];
    #pragma unroll
    for (int j = 0; j < 4; ++j) {
      int r = wr + (l >> 4) * 4 + j;
      float mean = (ps[0][r] + ps[1][r]) * (1.0f / 128.0f);
      float var = (psq[0][r] + psq[1][r]) * (1.0f / 128.0f) - mean * mean;
      float rstd = rsqrtf(var + 1e-5f);
      float s2 = 0.f, sq2 = 0.f;
      #pragma unroll
      for (int ni = 0; ni < NI; ++ni) {
        float t = (acc[0][ni][j] - mean) * rstd * gsv[ni] + gbv[ni];
        acc[0][ni][j] = t;
        s2 += t; sq2 = fmaf(t, t, sq2);
      }
      s2v[j] = s2; sq2v[j] = sq2;
    }
    __syncthreads();                 // all waves done reading stats1
    #pragma unroll
    for (int j = 0; j < 4; ++j) {
      int r = wr + (l >> 4) * 4 + j;
      float s = s2v[j], sq = sq2v[j];
      #pragma unroll
      for (int m = 1; m <= 8; m <<= 1) { s += __shfl_xor(s, m); sq += __shfl_xor(sq, m); }
      if ((l & 15) == 0) { ps[w & 1][r] = s; psq[w & 1][r] = sq; }
    }
    __syncthreads();
    // LN2 + head partials
    float p0v[4], p1v[4];
    #pragma unroll
    for (int j = 0; j < 4; ++j) {
      int r = wr + (l >> 4) * 4 + j;
      float mean = (ps[0][r] + ps[1][r]) * (1.0f / 128.0f);
      float var = (psq[0][r] + psq[1][r]) * (1.0f / 128.0f) - mean * mean;
      float rstd = rsqrtf(var + 1e-5f);
      float p0 = 0.f, p1 = 0.f;
      #pragma unroll
      for (int ni = 0; ni < NI; ++ni) {
        float ln = (acc[0][ni][j] - mean) * rstd * hsv[ni] + hbv[ni];
        p0 = fmaf(ln, hw0[ni], p0);
        p1 = fmaf(ln, hw1[ni], p1);
      }
      #pragma unroll
      for (int m = 1; m <= 8; m <<= 1) { p0 += __shfl_xor(p0, m); p1 += __shfl_xor(p1, m); }
      p0v[j] = p0; p1v[j] = p1;
    }
    __syncthreads();                 // done reading stats2
    #pragma unroll
    for (int j = 0; j < 4; ++j) {
      int r = wr + (l >> 4) * 4 + j;
      if ((l & 15) == 0) { ps[w & 1][r] = p0v[j]; psq[w & 1][r] = p1v[j]; }
    }
    __syncthreads();
    if ((w & 1) == 0) {
      #pragma unroll
      for (int j = 0; j < 4; ++j) {
        int r = wr + (l >> 4) * 4 + j;
        if ((l & 15) == 0) {
          long row = mb + r;
          if (row < NN) {
            outp[row] = ps[0][r] + ps[1][r] + hbias[0];
            outp[NN + row] = psq[0][r] + psq[1][r] + hbias[1];
          }
        }
      }
    }
  }
}

// ---------------- CSR build ----------------
__global__ void edge_hist_kernel(const int* __restrict__ eidx, int* __restrict__ deg) {
  int e = blockIdx.x * 256 + threadIdx.x;
  if (e >= E2) return;
  int ei = e % EE, b = e / EE;
  atomicAdd(&deg[eidx[EE + ei] + b * NND], 1);
}

__global__ void scan2_kernel(const int* __restrict__ deg, int* __restrict__ indptr,
                             int* __restrict__ cursor) {
  __shared__ int part[1024];
  int t = threadIdx.x;
  const int CH = 20;
  int beg = t * CH, end = beg + CH;
  if (end > NN) end = NN;
  if (beg > NN) beg = NN;
  int s = 0;
  for (int i = beg; i < end; ++i) s += deg[i];
  part[t] = s;
  __syncthreads();
  for (int off = 1; off < 1024; off <<= 1) {
    int add = (t >= off) ? part[t - off] : 0;
    __syncthreads();
    part[t] += add;
    __syncthreads();
  }
  int run = part[t] - s;
  for (int i = beg; i < end; ++i) {
    indptr[i] = run; cursor[i] = run; run += deg[i];
  }
  if (t == 0) indptr[NN] = E2;
}

__global__ void edge_scatter_kernel(const int* __restrict__ eidx, int* __restrict__ cursor,
                                    int* __restrict__ ssrc) {
  int e = blockIdx.x * 256 + threadIdx.x;
  if (e >= E2) return;
  int ei = e % EE, b = e / EE;
  int srcn = eidx[ei] + b * NND;
  int dstn = eidx[EE + ei] + b * NND;
  int pos = atomicAdd(&cursor[dstn], 1);
  ssrc[pos] = srcn;
}

// ---------------- fused flash-style edge attention (defer-max + 2-deep prefetch) ----------------
// 1 wave/node; 4 edges in flight per step (16 lanes each), TWO K/V register slots
// (statically indexed, rule #20) -> 8 outstanding edge-gathers per wave. [r5-optimal:
// depth 3 (+7us) and 8-lane groups (+20us) both measured worse]
// Q from R1 (stride 128); K|V gathered from R2 (stride 256; K at 0, V at 128).
// agg -> hpk[:,128:256].
__global__ __launch_bounds__(256) void fused_attn(
    const unsigned short* __restrict__ q1, const unsigned short* __restrict__ kv,
    const int* __restrict__ ssrc, const int* __restrict__ indptr,
    unsigned short* __restrict__ hpk) {
  int w = threadIdx.x >> 6, l = threadIdx.x & 63;
  int blk = blockIdx.x;
  // bijective batch swizzle (grid = 5000 = 625*8): xcd = blk%8; batch = bit2 of xcd
  int b = (blk >> 2) & 1;
  int i4 = (blk >> 3) * 4 + (blk & 3);      // 0..2499 within batch
  int node = b * NND + i4 * 4 + w;
  int g = l >> 4, sub = l & 15;
  int beg = indptr[node], end = indptr[node + 1];
  bf16x8 qreg = *(const bf16x8*)(q1 + (size_t)node * 128 + sub * 8);
  const unsigned short* qu = (const unsigned short*)&qreg;
  float m = -INFINITY, den = 0.f;
  float agg[8] = {};
  int p = beg + g;
  bf16x8 kreg0, vreg0, kreg1, vreg1;
  if (p < end) {            // preload slot 0 (edge p)
    const unsigned short* base = kv + (size_t)ssrc[p] * 256;
    kreg0 = *(const bf16x8*)(base + sub * 8);
    vreg0 = *(const bf16x8*)(base + 128 + sub * 8);
  }
  if (p + 4 < end) {        // preload slot 1 (edge p+4)
    const unsigned short* base = kv + (size_t)ssrc[p + 4] * 256;
    kreg1 = *(const bf16x8*)(base + sub * 8);
    vreg1 = *(const bf16x8*)(base + 128 + sub * 8);
  }

  auto process = [&](bf16x8 kcur, bf16x8 vcur) {
    const unsigned short* ku = (const unsigned short*)&kcur;
    const unsigned short* vu = (const unsigned short*)&vcur;
    float s = 0.f;
    #pragma unroll
    for (int j = 0; j < 8; ++j) s = fmaf(b2f(qu[j]), b2f(ku[j]), s);
    s += __shfl_xor(s, 1);
    s += __shfl_xor(s, 2);
    s += __shfl_xor(s, 4);
    s += __shfl_xor(s, 8);
    s *= SCALE;
    if (s > m + 8.f) {          // defer-max (T13): rescale only on large jumps
      float sc = __expf(m - s); // -inf first time -> 0
      den *= sc;
      #pragma unroll
      for (int j = 0; j < 8; ++j) agg[j] *= sc;
      m = s;
    }
    float e = __expf(s - m);    // bounded by e^8
    den += e;
    #pragma unroll
    for (int j = 0; j < 8; ++j) agg[j] = fmaf(e, b2f(vu[j]), agg[j]);
  };

  while (p < end) {
    {   // consume slot 0; refill with edge p+8
      bf16x8 kcur = kreg0, vcur = vreg0;
      if (p + 8 < end) {
        const unsigned short* base = kv + (size_t)ssrc[p + 8] * 256;
        kreg0 = *(const bf16x8*)(base + sub * 8);
        vreg0 = *(const bf16x8*)(base + 128 + sub * 8);
      }
      process(kcur, vcur);
      p += 4;
      if (p >= end) break;
    }
    {   // consume slot 1; refill with edge p+8
      bf16x8 kcur = kreg1, vcur = vreg1;
      if (p + 8 < end) {
        const unsigned short* base = kv + (size_t)ssrc[p + 8] * 256;
        kreg1 = *(const bf16x8*)(base + sub * 8);
        vreg1 = *(const bf16x8*)(base + 128 + sub * 8);
      }
      process(kcur, vcur);
      p += 4;
    }
  }

  if (beg < end) {
    float M = m;
    M = fmaxf(M, __shfl_xor(M, 16));
    M = fmaxf(M, __shfl_xor(M, 32));
    float sc = __expf(m - M);   // empty group: m=-inf -> 0
    den *= sc;
    #pragma unroll
    for (int j = 0; j < 8; ++j) agg[j] *= sc;
    den += __shfl_xor(den, 16);
    den += __shfl_xor(den, 32);
    #pragma unroll
    for (int j = 0; j < 8; ++j) {
      agg[j] += __shfl_xor(agg[j], 16);
      agg[j] += __shfl_xor(agg[j], 32);
    }
    float inv = 1.0f / fmaxf(den, 1e-12f);
    #pragma unroll
    for (int j = 0; j < 8; ++j) agg[j] *= inv;
  }
  if (g == 0) {
    unsigned short o[8];
    #pragma unroll
    for (int j = 0; j < 8; ++j) o[j] = f2b(agg[j]);
    *(u32x4*)(hpk + (size_t)node * HSTR + 128 + sub * 8) = *(const u32x4*)o;
  }
}

extern "C" void kernel_launch(void* const* d_in, const int* in_sizes, int n_in,
                              void* d_out, int out_size, void* d_ws, size_t ws_size,
                              hipStream_t stream) {
  const float* x        = (const float*)d_in[0];
  const int*   eidx     = (const int*)d_in[1];
  const float* node_emb = (const float*)d_in[2];
  const float* W_in     = (const float*)d_in[3];
  const float* b_in     = (const float*)d_in[4];
  const float* g1w      = (const float*)d_in[5];
  const float* g1b      = (const float*)d_in[6];
  const float* g2w      = (const float*)d_in[7];
  const float* g2b      = (const float*)d_in[8];
  const float* qw       = (const float*)d_in[9];
  const float* kw       = (const float*)d_in[10];
  const float* vw       = (const float*)d_in[11];
  const float* sw       = (const float*)d_in[12];
  const float* ow       = (const float*)d_in[13];
  const float* qb       = (const float*)d_in[14];
  const float* kb       = (const float*)d_in[15];
  const float* vb       = (const float*)d_in[16];
  const float* sb       = (const float*)d_in[17];
  const float* ob       = (const float*)d_in[18];
  const float* n1s      = (const float*)d_in[19];
  const float* n1b      = (const float*)d_in[20];
  const float* f1w      = (const float*)d_in[21];
  const float* f1b      = (const float*)d_in[22];
  const float* f2w      = (const float*)d_in[23];
  const float* f2b_     = (const float*)d_in[24];
  const float* n2s      = (const float*)d_in[25];
  const float* n2b      = (const float*)d_in[26];
  const float* hs       = (const float*)d_in[27];
  const float* hb       = (const float*)d_in[28];
  const float* head_w   = (const float*)d_in[29];
  const float* head_b   = (const float*)d_in[30];
  float* out = (float*)d_out;

  float* wsf = (float*)d_ws;
  size_t off = 0;
  auto alloc = [&](size_t nelem) {
    float* p = wsf + off;
    off += (nelem + 63) & ~(size_t)63;
    return p;
  };
  float* gamma  = alloc(BB * DD);
  float* beta   = alloc(BB * DD);
  float* h      = alloc((size_t)MP * DD);
  unsigned short* hpk   = (unsigned short*)alloc((size_t)MP * HSTR / 2);  // h | agg, bf16
  unsigned short* R     = (unsigned short*)alloc((size_t)MP * DFF / 2);   // ff1 out (512)
  unsigned short* R1    = (unsigned short*)alloc((size_t)MP * DD / 2);    // Q, stride 128
  unsigned short* R2    = (unsigned short*)alloc((size_t)MP * 256 / 2);   // K|V, stride 256
  unsigned short* featb = (unsigned short*)alloc((size_t)MP * FSTR / 2);
  int* deg    = (int*)alloc(NN);
  int* indptr = (int*)alloc(NN + 1);
  int* cursor = (int*)alloc(NN);
  int* ssrc   = (int*)alloc(E2);
  unsigned short* wqkvb = (unsigned short*)alloc((size_t)NLAYERS * 384 * DD / 2);
  unsigned short* wsow  = (unsigned short*)alloc((size_t)NLAYERS * DD * 256 / 2);
  unsigned short* f1wb  = (unsigned short*)alloc((size_t)NLAYERS * DFF * DD / 2);
  unsigned short* f2wb  = (unsigned short*)alloc((size_t)NLAYERS * DD * DFF / 2);
  unsigned short* wfeat = (unsigned short*)alloc((size_t)DD * FSTR / 2);
  float* qkvbias = alloc((size_t)NLAYERS * 384);
  float* sobias  = alloc((size_t)NLAYERS * DD);

  if (ws_size < off * sizeof(float)) return;  // clean bail

  // all packing / conversion / zeroing + gate MLP in one dispatch (+1 block for gate)
  mega_pack<<<(int)((OTOT + 255) / 256) + 1, 256, 0, stream>>>(
      qw, kw, vw, sw, ow, qb, kb, vb, sb, ob, f1w, f2w, W_in, x, node_emb,
      g1w, g1b, g2w, g2b,
      wqkvb, wsow, f1wb, f2wb, wfeat, qkvbias, sobias, featb,
      deg, hpk + (size_t)NN * HSTR, gamma, beta);

  edge_hist_kernel<<<(E2 + 255) / 256, 256, 0, stream>>>(eidx, deg);
  scan2_kernel<<<1, 1024, 0, stream>>>(deg, indptr, cursor);
  edge_scatter_kernel<<<(E2 + 255) / 256, 256, 0, stream>>>(eidx, cursor, ssrc);

  const int MB32 = MP / 32;    // 628
  const int MB64 = MP / 64;    // 314
  // input projection + FiLM (EPI=4, pipelined, BM=32)
  mfma_gemm<FSTR, FSTR, FSTR, 32, 128, 0, 4><<<dim3(MB32, 1), 256, 0, stream>>>(
      featb, wfeat, b_in, nullptr, 0, h, hpk, gamma, beta,
      nullptr, nullptr, nullptr, nullptr, nullptr);

  for (int i = 0; i < NLAYERS; ++i) {
    // fused q|k|v; Q -> R1 (128), K|V -> R2 (256)  (EPI=5, BM=64, 942 blocks)
    mfma_gemm<128, HSTR, 128, 64, 128, 0, 5><<<dim3(MB64, 3), 256, 0, stream>>>(
        hpk, wqkvb + (size_t)i * 384 * DD, qkvbias + i * 384, R1, 128,
        nullptr, R2, nullptr, nullptr,
        nullptr, nullptr, nullptr, nullptr, nullptr);
    // flash-style edge attention -> hpk[:,128:256]  (TLP-heavy: 5000 blocks)
    fused_attn<<<NN / 4, 256, 0, stream>>>(R1, R2, ssrc, indptr, hpk);
    // fused [h|agg] @ [sw|ow]^T + (sb+ob), relu, +h, LN  (EPI=2, pipelined, BM=32)
    mfma_gemm<256, HSTR, 256, 32, 128, 0, 2><<<dim3(MB32, 1), 256, 0, stream>>>(
        hpk, wsow + (size_t)i * DD * 256, sobias + i * DD, nullptr, 0,
        h, hpk, n1s + i * DD, n1b + i * DD,
        nullptr, nullptr, nullptr, nullptr, nullptr);
    // ff1 = gelu(h @ f1w^T + f1b) -> R [MP][512]  (BM=64, pipelined, 1256 blocks)
    mfma_gemm<128, HSTR, 128, 64, 128, 1, 0><<<dim3(MB64, 4), 256, 0, stream>>>(
        hpk, f1wb + (size_t)i * DFF * DD, f1b + i * DFF, R, 512,
        nullptr, nullptr, nullptr, nullptr,
        nullptr, nullptr, nullptr, nullptr, nullptr);
    // ff2 + resid + LN (layers 0-2) or + final LN + head (layer 3)
    if (i < NLAYERS - 1) {
      mfma_gemm<512, 512, 512, 32, 128, 0, 3><<<dim3(MB32, 1), 256, 0, stream>>>(
          R, f2wb + (size_t)i * DD * DFF, f2b_ + i * DD, nullptr, 0,
          h, hpk, n2s + i * DD, n2b + i * DD,
          nullptr, nullptr, nullptr, nullptr, nullptr);
    } else {
      mfma_gemm<512, 512, 512, 32, 128, 0, 6><<<dim3(MB32, 1), 256, 0, stream>>>(
          R, f2wb + (size_t)i * DD * DFF, f2b_ + i * DD, nullptr, 0,
          h, hpk, n2s + i * DD, n2b + i * DD,
          hs, hb, head_w, head_b, out);
    }
  }
}